// Round 3
// baseline (341.451 us; speedup 1.0000x reference)
//
#include <hip/hip_runtime.h>
#include <math.h>

// B=128, NU=32, NT=64, H=128, OUT_F=16, N_U=4096, N_A=8192
// Fully-bipartite-per-batch graph => segment-means are per-batch means.
// Single persistent kernel, 384 blocks x 256 threads, 4 grid barriers:
//  P0: weight-prep (96 blks) || embed+colmean+ant (128 blks)
//  P1: aggr it0 (128 hu-batch + 256 ha-half units; ha staged as ANT+noise)
//  P2: comb it0 (256 ha units -> ha2, 128 hu units -> hu2)
//  P3: aggr it1 (inputs hu2/ha2)
//  P4: comb it1 ha-side + fused final normalize -> out   (hu-side is dead)
// All GEMMs: bf16 MFMA 16x16x32 computing Y^T = W^T X^T (weights pre-
// transposed to [n][k]); C-layout writes land row-major for the next stage.

using frag  = __attribute__((ext_vector_type(8))) short;   // 8 x bf16
using f32x4 = __attribute__((ext_vector_type(4))) float;

#define LDST 136          // 128 + 8 pad (272B rows: 16B-aligned, 2-way banks = free)
#define NBLK 384

__device__ __forceinline__ float  bf2f(ushort u) { return __uint_as_float(((unsigned)u) << 16); }
__device__ __forceinline__ ushort f2bf(float f) {
    unsigned u = __float_as_uint(f);
    u += 0x7fff + ((u >> 16) & 1);            // RNE
    return (ushort)(u >> 16);
}

struct GP {
    const float *uf, *noise, *W_ue, *b_ue, *W_t, *b_t;
    const float *wsrc[12];    // fp32 weights for prep (slot order below)
    const float *bias6[6];    // ca_aggr_b, ca_self_b, ca_comb_b, cu_aggr_b, cu_self_b, cu_comb_b
    const float *Wn, *bn;
    float *out;
    ushort *WtAll, *hu, *hu2, *ha2, *ANT;
    float *SA, *SU;
    unsigned *cnt;
};
// WtAll slots: 0,1 ca_aggr L0/L1; 2,3 ca_self; 4,5 ca_comb; 6,7 cu_aggr; 8,9 cu_self; 10,11 cu_comb

// ---- device-scope grid barrier (monotone counter; memset to 0 each launch) ----
__device__ __forceinline__ void gbar(unsigned* cnt, unsigned target) {
    __syncthreads();                       // drains vmcnt: block's writes are in L2
    if (threadIdx.x == 0) {
        __threadfence();                   // agent-scope writeback
        __hip_atomic_fetch_add(cnt, 1u, __ATOMIC_RELEASE, __HIP_MEMORY_SCOPE_AGENT);
        while (__hip_atomic_load(cnt, __ATOMIC_ACQUIRE, __HIP_MEMORY_SCOPE_AGENT) < target)
            __builtin_amdgcn_s_sleep(2);
    }
    __syncthreads();
}

// ---- one MLP stage on 32 rows: Y = relu(X @ W + b) (+ optional meanL add) ----
// Wt is [n][k] with stride wstride (128 = global WtAll, LDST = LDS copy).
template<bool MEANADD>
__device__ __forceinline__ void mlp_stage(const ushort* Xl, ushort* Yl,
    const ushort* Wt, int wstride, const float* __restrict__ bias, const float* meanL)
{
    const int lane = threadIdx.x & 63, wave = threadIdx.x >> 6;
    const int q = lane >> 4, l15 = lane & 15;
    frag A[2][4];
#pragma unroll
    for (int i = 0; i < 2; ++i) {
        const int n0 = (wave * 2 + i) * 16;
#pragma unroll
        for (int kc = 0; kc < 4; ++kc)
            A[i][kc] = *(const frag*)(Wt + (n0 + l15) * wstride + kc * 32 + q * 8);
    }
#pragma unroll
    for (int mt = 0; mt < 2; ++mt) {
        frag Bv[4];
#pragma unroll
        for (int kc = 0; kc < 4; ++kc)
            Bv[kc] = *(const frag*)(Xl + (mt * 16 + l15) * LDST + kc * 32 + q * 8);
#pragma unroll
        for (int i = 0; i < 2; ++i) {
            f32x4 acc = {0.f, 0.f, 0.f, 0.f};
#pragma unroll
            for (int kc = 0; kc < 4; ++kc)
                acc = __builtin_amdgcn_mfma_f32_16x16x32_bf16(A[i][kc], Bv[kc], acc, 0, 0, 0);
            const int n0 = (wave * 2 + i) * 16 + q * 4;
            const float4 bv = *(const float4*)(bias + n0);
            float v0 = acc[0] + bv.x, v1 = acc[1] + bv.y, v2 = acc[2] + bv.z, v3 = acc[3] + bv.w;
            v0 = v0 > 0.f ? v0 : 0.f; v1 = v1 > 0.f ? v1 : 0.f;
            v2 = v2 > 0.f ? v2 : 0.f; v3 = v3 > 0.f ? v3 : 0.f;
            if (MEANADD) {
                const float4 mv = *(const float4*)(meanL + n0);
                v0 += mv.x; v1 += mv.y; v2 += mv.z; v3 += mv.w;
            }
            ushort4 o = { f2bf(v0), f2bf(v1), f2bf(v2), f2bf(v3) };
            *(ushort4*)(Yl + (mt * 16 + l15) * LDST + n0) = o;
        }
    }
}

// ---- staging helpers (32 rows) ----
__device__ __forceinline__ void stage_bf16_32(ushort* Xl, const ushort* __restrict__ src) {
    for (int c = threadIdx.x; c < 32 * 16; c += 256) {
        const int r = c >> 4, k8 = c & 15;
        *(uint4*)(Xl + r * LDST + k8 * 8) = *(const uint4*)(src + r * 128 + k8 * 8);
    }
}
__device__ __forceinline__ void stage_f32_32(ushort* Xl, const float* __restrict__ src) {
    for (int c = threadIdx.x; c < 32 * 32; c += 256) {
        const int r = c >> 5, k4 = c & 31;
        const float4 v = *(const float4*)(src + r * 128 + k4 * 4);
        ushort4 o = { f2bf(v.x), f2bf(v.y), f2bf(v.z), f2bf(v.w) };
        *(ushort4*)(Xl + r * LDST + k4 * 4) = o;
    }
}
__device__ __forceinline__ void stage_ha_32(ushort* Xl, const float* __restrict__ noise,
                                            const ushort* __restrict__ ant) {
    for (int c = threadIdx.x; c < 32 * 32; c += 256) {
        const int r = c >> 5, k4 = c & 31;
        const float4 v = *(const float4*)(noise + r * 128 + k4 * 4);
        const ushort4 a = *(const ushort4*)(ant + k4 * 4);
        ushort4 o = { f2bf(v.x + bf2f(a.x)), f2bf(v.y + bf2f(a.y)),
                      f2bf(v.z + bf2f(a.z)), f2bf(v.w + bf2f(a.w)) };
        *(ushort4*)(Xl + r * LDST + k4 * 4) = o;
    }
}
__device__ __forceinline__ void writeout_32(ushort* __restrict__ dst, const ushort* Yl) {
    for (int c = threadIdx.x; c < 32 * 16; c += 256) {
        const int r = c >> 4, k8 = c & 15;
        *(uint4*)(dst + r * 128 + k8 * 8) = *(const uint4*)(Yl + r * LDST + k8 * 8);
    }
}

// ---- weight transpose: fp32 [k][n] -> bf16 [n][k] (one 16-k slab per call) ----
__device__ __forceinline__ void wslab(ushort* dst, int dstride, float* slab,
                                      const float* __restrict__ W, int kb)
{
    for (int c = threadIdx.x; c < 512; c += 256) {
        const int kr = c >> 5, c4 = c & 31;
        const float4 v = *(const float4*)(W + (kb * 16 + kr) * 128 + c4 * 4);
        slab[kr * 129 + c4 * 4 + 0] = v.x; slab[kr * 129 + c4 * 4 + 1] = v.y;
        slab[kr * 129 + c4 * 4 + 2] = v.z; slab[kr * 129 + c4 * 4 + 3] = v.w;
    }
    __syncthreads();
    for (int c = threadIdx.x; c < 1024; c += 256) {
        const int n = c >> 3, k2 = c & 7;
        const unsigned d = (unsigned)f2bf(slab[(2 * k2) * 129 + n])
                         | ((unsigned)f2bf(slab[(2 * k2 + 1) * 129 + n]) << 16);
        *(unsigned*)(dst + n * dstride + kb * 16 + 2 * k2) = d;
    }
    __syncthreads();
}

// ---- phase cores ----
__device__ __forceinline__ void aggr_core(ushort* buf0, ushort* buf1,
    const ushort* WtAll, int slot, const float* bias2, float* __restrict__ sumout, float scale)
{
    __syncthreads();
    mlp_stage<false>(buf0, buf1, WtAll + slot * 16384, 128, bias2, nullptr);
    __syncthreads();
    mlp_stage<false>(buf1, buf0, WtAll + (slot + 1) * 16384, 128, bias2 + 128, nullptr);
    __syncthreads();
    const int t = threadIdx.x;
    if (t < 128) {
        float s = 0.f;
        for (int r = 0; r < 32; ++r) s += bf2f(buf0[r * LDST + t]);
        sumout[t] = s * scale;
    }
}

template<bool FINAL>
__device__ __forceinline__ void comb_core(ushort* buf0, ushort* buf1, const float* meanL,
    const ushort* WtAll, int sslot, int cslot, const float* sbias, const float* cbias,
    ushort* __restrict__ dstg, const float* WnS, const float* __restrict__ bn,
    float* __restrict__ out, int r0)
{
    __syncthreads();
    mlp_stage<false>(buf0, buf1, WtAll + sslot * 16384, 128, sbias, nullptr);
    __syncthreads();
    mlp_stage<true >(buf1, buf0, WtAll + (sslot + 1) * 16384, 128, sbias + 128, meanL);
    __syncthreads();
    mlp_stage<false>(buf0, buf1, WtAll + cslot * 16384, 128, cbias, nullptr);
    __syncthreads();
    mlp_stage<false>(buf1, buf0, WtAll + (cslot + 1) * 16384, 128, cbias + 128, nullptr);
    __syncthreads();
    if (FINAL) {
        const int t = threadIdx.x, row = t >> 3, j = t & 7;
        float R = bn[j], I = bn[j + 8];
        const ushort* h = buf0 + row * LDST;
        for (int k = 0; k < 128; ++k) {
            const float hv = bf2f(h[k]);
            R += hv * WnS[k * 16 + j];
            I += hv * WnS[k * 16 + j + 8];
        }
        const float mag = sqrtf(R * R + I * I);
        const int a = r0 + row;
        out[a * 16 + j]     = R / mag;
        out[a * 16 + j + 8] = I / mag;
    } else {
        writeout_32(dstg, buf0);
    }
}

__global__ __launch_bounds__(256, 2) void k_gnn(GP P)
{
    __shared__ __align__(16) ushort buf0[32 * LDST];
    __shared__ __align__(16) ushort buf1[32 * LDST];
    __shared__ __align__(16) ushort WtL[128 * LDST];   // embed W_ue^T; reused as WnS in P4
    __shared__ __align__(16) float  meanL[128];
    const int blk = blockIdx.x;
    const int tid = threadIdx.x;
    float* slab = (float*)buf0;   // 16x129 fp32 transpose temp (8256 B <= buf0)

    // ================= P0: weight prep || embed+ant =================
    if (blk < 96) {
        wslab(P.WtAll + (blk >> 3) * 16384, 128, slab, P.wsrc[blk >> 3], blk & 7);
    } else if (blk < 224) {
        const int b = blk - 96;
        for (int kb = 0; kb < 8; ++kb) wslab(WtL, LDST, slab, P.W_ue, kb);
        stage_f32_32(buf0, P.uf + (size_t)b * 32 * 128);
        __syncthreads();
        mlp_stage<false>(buf0, buf1, WtL, LDST, P.b_ue, nullptr);
        __syncthreads();
        writeout_32(P.hu + (size_t)b * 32 * 128, buf1);
        if (tid < 128) {                               // per-batch colmean (in LDS)
            float s = 0.f;
            for (int r = 0; r < 32; ++r) s += bf2f(buf1[r * LDST + tid]);
            meanL[tid] = s * (1.f / 32.f);
        }
        __syncthreads();
        if (tid < 128) {                               // ant[b] = relu(mean @ W_t + b_t), fp32
            float acc = P.b_t[tid];
            for (int k = 0; k < 128; ++k) acc += meanL[k] * P.W_t[k * 128 + tid];
            P.ANT[b * 128 + tid] = f2bf(acc > 0.f ? acc : 0.f);
        }
    }
    gbar(P.cnt, 1 * NBLK);

    // ================= P1: aggr it0 =================
    if (blk < 128) {             // msg = mlp2(hu[batch]) -> SA[b] (mean, deg 32)
        stage_bf16_32(buf0, P.hu + (size_t)blk * 32 * 128);
        aggr_core(buf0, buf1, P.WtAll, 0, P.bias6[0], P.SA + blk * 128, 1.f / 32.f);
    } else {                     // msg = mlp2(ha half-batch) -> SU[v] (raw colsum)
        const int v = blk - 128;
        stage_ha_32(buf0, P.noise + (size_t)v * 32 * 128, P.ANT + (v >> 1) * 128);
        aggr_core(buf0, buf1, P.WtAll, 6, P.bias6[3], P.SU + v * 128, 1.f);
    }
    gbar(P.cnt, 2 * NBLK);

    // ================= P2: comb it0 =================
    if (blk < 256) {             // na: 32 ha rows -> ha2
        const int r0 = blk * 32, b = blk >> 1;
        stage_ha_32(buf0, P.noise + (size_t)r0 * 128, P.ANT + b * 128);
        if (tid < 128) meanL[tid] = P.SA[b * 128 + tid];
        comb_core<false>(buf0, buf1, meanL, P.WtAll, 2, 4, P.bias6[1], P.bias6[2],
                         P.ha2 + (size_t)r0 * 128, nullptr, nullptr, nullptr, 0);
    } else {                     // nu: 32 hu rows -> hu2
        const int b = blk - 256, r0 = b * 32;
        stage_bf16_32(buf0, P.hu + (size_t)r0 * 128);
        if (tid < 128)
            meanL[tid] = (P.SU[(2 * b) * 128 + tid] + P.SU[(2 * b + 1) * 128 + tid]) * (1.f / 64.f);
        comb_core<false>(buf0, buf1, meanL, P.WtAll, 8, 10, P.bias6[4], P.bias6[5],
                         P.hu2 + (size_t)r0 * 128, nullptr, nullptr, nullptr, 0);
    }
    gbar(P.cnt, 3 * NBLK);

    // ================= P3: aggr it1 (inputs hu2/ha2) =================
    if (blk < 128) {
        stage_bf16_32(buf0, P.hu2 + (size_t)blk * 32 * 128);
        aggr_core(buf0, buf1, P.WtAll, 0, P.bias6[0], P.SA + blk * 128, 1.f / 32.f);
    } else {
        const int v = blk - 128;
        stage_bf16_32(buf0, P.ha2 + (size_t)v * 32 * 128);
        aggr_core(buf0, buf1, P.WtAll, 6, P.bias6[3], P.SU + v * 128, 1.f);
    }
    gbar(P.cnt, 4 * NBLK);

    // ================= P4: comb it1 (ha only) + fused final =================
    if (blk < 256) {
        const int r0 = blk * 32, b = blk >> 1;
        stage_bf16_32(buf0, P.ha2 + (size_t)r0 * 128);
        float* WnS = (float*)WtL;
        for (int c = tid; c < 512; c += 256)
            *(float4*)(WnS + c * 4) = *(const float4*)(P.Wn + c * 4);
        if (tid < 128) meanL[tid] = P.SA[b * 128 + tid];
        comb_core<true>(buf0, buf1, meanL, P.WtAll, 2, 4, P.bias6[1], P.bias6[2],
                        nullptr, WnS, P.bn, P.out, r0);
    }
}

extern "C" void kernel_launch(void* const* d_in, const int* in_sizes, int n_in,
                              void* d_out, int out_size, void* d_ws, size_t ws_size,
                              hipStream_t stream)
{
    GP P;
    P.uf    = (const float*)d_in[0];
    P.noise = (const float*)d_in[1];
    P.W_ue  = (const float*)d_in[6];
    P.b_ue  = (const float*)d_in[7];
    P.W_t   = (const float*)d_in[8];
    P.b_t   = (const float*)d_in[9];
    const float* caW[3] = {(const float*)d_in[10], (const float*)d_in[12], (const float*)d_in[14]};
    const float* cab[3] = {(const float*)d_in[11], (const float*)d_in[13], (const float*)d_in[15]};
    const float* cuW[3] = {(const float*)d_in[16], (const float*)d_in[18], (const float*)d_in[20]};
    const float* cub[3] = {(const float*)d_in[17], (const float*)d_in[19], (const float*)d_in[21]};
    P.Wn  = (const float*)d_in[22];
    P.bn  = (const float*)d_in[23];
    P.out = (float*)d_out;

    P.wsrc[0]  = caW[0]; P.wsrc[1]  = caW[0] + 16384;
    P.wsrc[2]  = caW[1]; P.wsrc[3]  = caW[1] + 16384;
    P.wsrc[4]  = caW[2]; P.wsrc[5]  = caW[2] + 16384;
    P.wsrc[6]  = cuW[0]; P.wsrc[7]  = cuW[0] + 16384;
    P.wsrc[8]  = cuW[1]; P.wsrc[9]  = cuW[1] + 16384;
    P.wsrc[10] = cuW[2]; P.wsrc[11] = cuW[2] + 16384;
    P.bias6[0] = cab[0]; P.bias6[1] = cab[1]; P.bias6[2] = cab[2];
    P.bias6[3] = cub[0]; P.bias6[4] = cub[1]; P.bias6[5] = cub[2];

    char* w = (char*)d_ws;
    P.cnt   = (unsigned*)w;                          // 256 B reserved
    P.WtAll = (ushort*)(w + 256);                    // 12*16384 bf16
    P.hu    = P.WtAll + 12 * 16384;                  // 4096*128
    P.hu2   = P.hu  + 4096 * 128;
    P.ha2   = P.hu2 + 4096 * 128;                    // 8192*128
    P.ANT   = P.ha2 + 8192 * 128;                    // 128*128
    P.SA    = (float*)(P.ANT + 128 * 128);           // 128*128 fp32 (scaled means)
    P.SU    = P.SA + 128 * 128;                      // 256*128 fp32 (half-batch colsums)

    hipMemsetAsync(P.cnt, 0, 256, stream);
    k_gnn<<<dim3(NBLK), dim3(256), 0, stream>>>(P);
}

// Round 4
// 234.339 us; speedup vs baseline: 1.4571x; 1.4571x over previous
//
#include <hip/hip_runtime.h>
#include <math.h>

// B=128, NU=32, NT=64, H=128, OUT_F=16, N_U=4096, N_A=8192
// Fully-bipartite-per-batch graph => segment-means are per-batch means.
// Single persistent kernel, 384 blocks x 256 threads, 4 grid barriers:
//  P0: weight-prep (96 blks) || embed+colmean+ant (128 blks)
//  P1: aggr it0 (128 hu-batch + 256 ha-half units; ha staged as ANT+noise)
//  P2: comb it0 (256 ha units -> ha2, 128 hu units -> hu2)
//  P3: aggr it1 (inputs hu2/ha2)
//  P4: comb it1 ha-side + fused final normalize -> out   (hu-side is dead)
// All GEMMs: bf16 MFMA 16x16x32 computing Y^T = W^T X^T (weights pre-
// transposed to [n][k]); C-layout writes land row-major for the next stage.
//
// R4 change: grid barrier polls with RELAXED atomic (plain sc1 load, no
// buffer_inv) + single ACQUIRE after the target is seen. R3's ACQUIRE-per-
// poll emitted an L2 invalidate per poll from 384 spinners -> cache storm
// (243 us kernel, MfmaUtil 0.7%).

using frag  = __attribute__((ext_vector_type(8))) short;   // 8 x bf16
using f32x4 = __attribute__((ext_vector_type(4))) float;

#define LDST 136          // 128 + 8 pad (272B rows: 16B-aligned, 2-way banks = free)
#define NBLK 384

__device__ __forceinline__ float  bf2f(ushort u) { return __uint_as_float(((unsigned)u) << 16); }
__device__ __forceinline__ ushort f2bf(float f) {
    unsigned u = __float_as_uint(f);
    u += 0x7fff + ((u >> 16) & 1);            // RNE
    return (ushort)(u >> 16);
}

struct GP {
    const float *uf, *noise, *W_ue, *b_ue, *W_t, *b_t;
    const float *wsrc[12];    // fp32 weights for prep (slot order below)
    const float *bias6[6];    // ca_aggr_b, ca_self_b, ca_comb_b, cu_aggr_b, cu_self_b, cu_comb_b
    const float *Wn, *bn;
    float *out;
    ushort *WtAll, *hu, *hu2, *ha2, *ANT;
    float *SA, *SU;
    unsigned *cnt;
};
// WtAll slots: 0,1 ca_aggr L0/L1; 2,3 ca_self; 4,5 ca_comb; 6,7 cu_aggr; 8,9 cu_self; 10,11 cu_comb

// ---- device-scope grid barrier (monotone counter; memset to 0 each launch) ----
// RELEASE on the increment publishes this block's writes; RELAXED polling (no
// cache invalidate per poll); ONE ACQUIRE load once target is reached.
__device__ __forceinline__ void gbar(unsigned* cnt, unsigned target) {
    __syncthreads();
    if (threadIdx.x == 0) {
        __hip_atomic_fetch_add(cnt, 1u, __ATOMIC_RELEASE, __HIP_MEMORY_SCOPE_AGENT);
        while (__hip_atomic_load(cnt, __ATOMIC_RELAXED, __HIP_MEMORY_SCOPE_AGENT) < target)
            __builtin_amdgcn_s_sleep(16);
        (void)__hip_atomic_load(cnt, __ATOMIC_ACQUIRE, __HIP_MEMORY_SCOPE_AGENT);
    }
    __syncthreads();
}

// ---- one MLP stage on 32 rows: Y = relu(X @ W + b) (+ optional meanL add) ----
// Wt is [n][k] with stride wstride (128 = global WtAll, LDST = LDS copy).
template<bool MEANADD>
__device__ __forceinline__ void mlp_stage(const ushort* Xl, ushort* Yl,
    const ushort* Wt, int wstride, const float* __restrict__ bias, const float* meanL)
{
    const int lane = threadIdx.x & 63, wave = threadIdx.x >> 6;
    const int q = lane >> 4, l15 = lane & 15;
    frag A[2][4];
#pragma unroll
    for (int i = 0; i < 2; ++i) {
        const int n0 = (wave * 2 + i) * 16;
#pragma unroll
        for (int kc = 0; kc < 4; ++kc)
            A[i][kc] = *(const frag*)(Wt + (n0 + l15) * wstride + kc * 32 + q * 8);
    }
#pragma unroll
    for (int mt = 0; mt < 2; ++mt) {
        frag Bv[4];
#pragma unroll
        for (int kc = 0; kc < 4; ++kc)
            Bv[kc] = *(const frag*)(Xl + (mt * 16 + l15) * LDST + kc * 32 + q * 8);
#pragma unroll
        for (int i = 0; i < 2; ++i) {
            f32x4 acc = {0.f, 0.f, 0.f, 0.f};
#pragma unroll
            for (int kc = 0; kc < 4; ++kc)
                acc = __builtin_amdgcn_mfma_f32_16x16x32_bf16(A[i][kc], Bv[kc], acc, 0, 0, 0);
            const int n0 = (wave * 2 + i) * 16 + q * 4;
            const float4 bv = *(const float4*)(bias + n0);
            float v0 = acc[0] + bv.x, v1 = acc[1] + bv.y, v2 = acc[2] + bv.z, v3 = acc[3] + bv.w;
            v0 = v0 > 0.f ? v0 : 0.f; v1 = v1 > 0.f ? v1 : 0.f;
            v2 = v2 > 0.f ? v2 : 0.f; v3 = v3 > 0.f ? v3 : 0.f;
            if (MEANADD) {
                const float4 mv = *(const float4*)(meanL + n0);
                v0 += mv.x; v1 += mv.y; v2 += mv.z; v3 += mv.w;
            }
            ushort4 o = { f2bf(v0), f2bf(v1), f2bf(v2), f2bf(v3) };
            *(ushort4*)(Yl + (mt * 16 + l15) * LDST + n0) = o;
        }
    }
}

// ---- staging helpers (32 rows) ----
__device__ __forceinline__ void stage_bf16_32(ushort* Xl, const ushort* __restrict__ src) {
    for (int c = threadIdx.x; c < 32 * 16; c += 256) {
        const int r = c >> 4, k8 = c & 15;
        *(uint4*)(Xl + r * LDST + k8 * 8) = *(const uint4*)(src + r * 128 + k8 * 8);
    }
}
__device__ __forceinline__ void stage_f32_32(ushort* Xl, const float* __restrict__ src) {
    for (int c = threadIdx.x; c < 32 * 32; c += 256) {
        const int r = c >> 5, k4 = c & 31;
        const float4 v = *(const float4*)(src + r * 128 + k4 * 4);
        ushort4 o = { f2bf(v.x), f2bf(v.y), f2bf(v.z), f2bf(v.w) };
        *(ushort4*)(Xl + r * LDST + k4 * 4) = o;
    }
}
__device__ __forceinline__ void stage_ha_32(ushort* Xl, const float* __restrict__ noise,
                                            const ushort* __restrict__ ant) {
    for (int c = threadIdx.x; c < 32 * 32; c += 256) {
        const int r = c >> 5, k4 = c & 31;
        const float4 v = *(const float4*)(noise + r * 128 + k4 * 4);
        const ushort4 a = *(const ushort4*)(ant + k4 * 4);
        ushort4 o = { f2bf(v.x + bf2f(a.x)), f2bf(v.y + bf2f(a.y)),
                      f2bf(v.z + bf2f(a.z)), f2bf(v.w + bf2f(a.w)) };
        *(ushort4*)(Xl + r * LDST + k4 * 4) = o;
    }
}
__device__ __forceinline__ void writeout_32(ushort* __restrict__ dst, const ushort* Yl) {
    for (int c = threadIdx.x; c < 32 * 16; c += 256) {
        const int r = c >> 4, k8 = c & 15;
        *(uint4*)(dst + r * 128 + k8 * 8) = *(const uint4*)(Yl + r * LDST + k8 * 8);
    }
}

// ---- weight transpose: fp32 [k][n] -> bf16 [n][k] (one 16-k slab per call) ----
__device__ __forceinline__ void wslab(ushort* dst, int dstride, float* slab,
                                      const float* __restrict__ W, int kb)
{
    for (int c = threadIdx.x; c < 512; c += 256) {
        const int kr = c >> 5, c4 = c & 31;
        const float4 v = *(const float4*)(W + (kb * 16 + kr) * 128 + c4 * 4);
        slab[kr * 129 + c4 * 4 + 0] = v.x; slab[kr * 129 + c4 * 4 + 1] = v.y;
        slab[kr * 129 + c4 * 4 + 2] = v.z; slab[kr * 129 + c4 * 4 + 3] = v.w;
    }
    __syncthreads();
    for (int c = threadIdx.x; c < 1024; c += 256) {
        const int n = c >> 3, k2 = c & 7;
        const unsigned d = (unsigned)f2bf(slab[(2 * k2) * 129 + n])
                         | ((unsigned)f2bf(slab[(2 * k2 + 1) * 129 + n]) << 16);
        *(unsigned*)(dst + n * dstride + kb * 16 + 2 * k2) = d;
    }
    __syncthreads();
}

// ---- phase cores ----
__device__ __forceinline__ void aggr_core(ushort* buf0, ushort* buf1,
    const ushort* WtAll, int slot, const float* bias2, float* __restrict__ sumout, float scale)
{
    __syncthreads();
    mlp_stage<false>(buf0, buf1, WtAll + slot * 16384, 128, bias2, nullptr);
    __syncthreads();
    mlp_stage<false>(buf1, buf0, WtAll + (slot + 1) * 16384, 128, bias2 + 128, nullptr);
    __syncthreads();
    const int t = threadIdx.x;
    if (t < 128) {
        float s = 0.f;
        for (int r = 0; r < 32; ++r) s += bf2f(buf0[r * LDST + t]);
        sumout[t] = s * scale;
    }
}

template<bool FINAL>
__device__ __forceinline__ void comb_core(ushort* buf0, ushort* buf1, const float* meanL,
    const ushort* WtAll, int sslot, int cslot, const float* sbias, const float* cbias,
    ushort* __restrict__ dstg, const float* WnS, const float* __restrict__ bn,
    float* __restrict__ out, int r0)
{
    __syncthreads();
    mlp_stage<false>(buf0, buf1, WtAll + sslot * 16384, 128, sbias, nullptr);
    __syncthreads();
    mlp_stage<true >(buf1, buf0, WtAll + (sslot + 1) * 16384, 128, sbias + 128, meanL);
    __syncthreads();
    mlp_stage<false>(buf0, buf1, WtAll + cslot * 16384, 128, cbias, nullptr);
    __syncthreads();
    mlp_stage<false>(buf1, buf0, WtAll + (cslot + 1) * 16384, 128, cbias + 128, nullptr);
    __syncthreads();
    if (FINAL) {
        const int t = threadIdx.x, row = t >> 3, j = t & 7;
        float R = bn[j], I = bn[j + 8];
        const ushort* h = buf0 + row * LDST;
        for (int k = 0; k < 128; ++k) {
            const float hv = bf2f(h[k]);
            R += hv * WnS[k * 16 + j];
            I += hv * WnS[k * 16 + j + 8];
        }
        const float mag = sqrtf(R * R + I * I);
        const int a = r0 + row;
        out[a * 16 + j]     = R / mag;
        out[a * 16 + j + 8] = I / mag;
    } else {
        writeout_32(dstg, buf0);
    }
}

__global__ __launch_bounds__(256, 2) void k_gnn(GP P)
{
    __shared__ __align__(16) ushort buf0[32 * LDST];
    __shared__ __align__(16) ushort buf1[32 * LDST];
    __shared__ __align__(16) ushort WtL[128 * LDST];   // embed W_ue^T; reused as WnS in P4
    __shared__ __align__(16) float  meanL[128];
    const int blk = blockIdx.x;
    const int tid = threadIdx.x;
    float* slab = (float*)buf0;   // 16x129 fp32 transpose temp (8256 B <= buf0)

    // ================= P0: weight prep || embed+ant =================
    if (blk < 96) {
        wslab(P.WtAll + (blk >> 3) * 16384, 128, slab, P.wsrc[blk >> 3], blk & 7);
    } else if (blk < 224) {
        const int b = blk - 96;
        for (int kb = 0; kb < 8; ++kb) wslab(WtL, LDST, slab, P.W_ue, kb);
        stage_f32_32(buf0, P.uf + (size_t)b * 32 * 128);
        __syncthreads();
        mlp_stage<false>(buf0, buf1, WtL, LDST, P.b_ue, nullptr);
        __syncthreads();
        writeout_32(P.hu + (size_t)b * 32 * 128, buf1);
        if (tid < 128) {                               // per-batch colmean (in LDS)
            float s = 0.f;
            for (int r = 0; r < 32; ++r) s += bf2f(buf1[r * LDST + tid]);
            meanL[tid] = s * (1.f / 32.f);
        }
        __syncthreads();
        if (tid < 128) {                               // ant[b] = relu(mean @ W_t + b_t), fp32
            float acc = P.b_t[tid];
            for (int k = 0; k < 128; ++k) acc += meanL[k] * P.W_t[k * 128 + tid];
            P.ANT[b * 128 + tid] = f2bf(acc > 0.f ? acc : 0.f);
        }
    }
    gbar(P.cnt, 1 * NBLK);

    // ================= P1: aggr it0 =================
    if (blk < 128) {             // msg = mlp2(hu[batch]) -> SA[b] (mean, deg 32)
        stage_bf16_32(buf0, P.hu + (size_t)blk * 32 * 128);
        aggr_core(buf0, buf1, P.WtAll, 0, P.bias6[0], P.SA + blk * 128, 1.f / 32.f);
    } else {                     // msg = mlp2(ha half-batch) -> SU[v] (raw colsum)
        const int v = blk - 128;
        stage_ha_32(buf0, P.noise + (size_t)v * 32 * 128, P.ANT + (v >> 1) * 128);
        aggr_core(buf0, buf1, P.WtAll, 6, P.bias6[3], P.SU + v * 128, 1.f);
    }
    gbar(P.cnt, 2 * NBLK);

    // ================= P2: comb it0 =================
    if (blk < 256) {             // na: 32 ha rows -> ha2
        const int r0 = blk * 32, b = blk >> 1;
        stage_ha_32(buf0, P.noise + (size_t)r0 * 128, P.ANT + b * 128);
        if (tid < 128) meanL[tid] = P.SA[b * 128 + tid];
        comb_core<false>(buf0, buf1, meanL, P.WtAll, 2, 4, P.bias6[1], P.bias6[2],
                         P.ha2 + (size_t)r0 * 128, nullptr, nullptr, nullptr, 0);
    } else {                     // nu: 32 hu rows -> hu2
        const int b = blk - 256, r0 = b * 32;
        stage_bf16_32(buf0, P.hu + (size_t)r0 * 128);
        if (tid < 128)
            meanL[tid] = (P.SU[(2 * b) * 128 + tid] + P.SU[(2 * b + 1) * 128 + tid]) * (1.f / 64.f);
        comb_core<false>(buf0, buf1, meanL, P.WtAll, 8, 10, P.bias6[4], P.bias6[5],
                         P.hu2 + (size_t)r0 * 128, nullptr, nullptr, nullptr, 0);
    }
    gbar(P.cnt, 3 * NBLK);

    // ================= P3: aggr it1 (inputs hu2/ha2) =================
    if (blk < 128) {
        stage_bf16_32(buf0, P.hu2 + (size_t)blk * 32 * 128);
        aggr_core(buf0, buf1, P.WtAll, 0, P.bias6[0], P.SA + blk * 128, 1.f / 32.f);
    } else {
        const int v = blk - 128;
        stage_bf16_32(buf0, P.ha2 + (size_t)v * 32 * 128);
        aggr_core(buf0, buf1, P.WtAll, 6, P.bias6[3], P.SU + v * 128, 1.f);
    }
    gbar(P.cnt, 4 * NBLK);

    // ================= P4: comb it1 (ha only) + fused final =================
    if (blk < 256) {
        const int r0 = blk * 32, b = blk >> 1;
        stage_bf16_32(buf0, P.ha2 + (size_t)r0 * 128);
        float* WnS = (float*)WtL;
        for (int c = tid; c < 512; c += 256)
            *(float4*)(WnS + c * 4) = *(const float4*)(P.Wn + c * 4);
        if (tid < 128) meanL[tid] = P.SA[b * 128 + tid];
        comb_core<true>(buf0, buf1, meanL, P.WtAll, 2, 4, P.bias6[1], P.bias6[2],
                        nullptr, WnS, P.bn, P.out, r0);
    }
}

extern "C" void kernel_launch(void* const* d_in, const int* in_sizes, int n_in,
                              void* d_out, int out_size, void* d_ws, size_t ws_size,
                              hipStream_t stream)
{
    GP P;
    P.uf    = (const float*)d_in[0];
    P.noise = (const float*)d_in[1];
    P.W_ue  = (const float*)d_in[6];
    P.b_ue  = (const float*)d_in[7];
    P.W_t   = (const float*)d_in[8];
    P.b_t   = (const float*)d_in[9];
    const float* caW[3] = {(const float*)d_in[10], (const float*)d_in[12], (const float*)d_in[14]};
    const float* cab[3] = {(const float*)d_in[11], (const float*)d_in[13], (const float*)d_in[15]};
    const float* cuW[3] = {(const float*)d_in[16], (const float*)d_in[18], (const float*)d_in[20]};
    const float* cub[3] = {(const float*)d_in[17], (const float*)d_in[19], (const float*)d_in[21]};
    P.Wn  = (const float*)d_in[22];
    P.bn  = (const float*)d_in[23];
    P.out = (float*)d_out;

    P.wsrc[0]  = caW[0]; P.wsrc[1]  = caW[0] + 16384;
    P.wsrc[2]  = caW[1]; P.wsrc[3]  = caW[1] + 16384;
    P.wsrc[4]  = caW[2]; P.wsrc[5]  = caW[2] + 16384;
    P.wsrc[6]  = cuW[0]; P.wsrc[7]  = cuW[0] + 16384;
    P.wsrc[8]  = cuW[1]; P.wsrc[9]  = cuW[1] + 16384;
    P.wsrc[10] = cuW[2]; P.wsrc[11] = cuW[2] + 16384;
    P.bias6[0] = cab[0]; P.bias6[1] = cab[1]; P.bias6[2] = cab[2];
    P.bias6[3] = cub[0]; P.bias6[4] = cub[1]; P.bias6[5] = cub[2];

    char* w = (char*)d_ws;
    P.cnt   = (unsigned*)w;                          // 256 B reserved
    P.WtAll = (ushort*)(w + 256);                    // 12*16384 bf16
    P.hu    = P.WtAll + 12 * 16384;                  // 4096*128
    P.hu2   = P.hu  + 4096 * 128;
    P.ha2   = P.hu2 + 4096 * 128;                    // 8192*128
    P.ANT   = P.ha2 + 8192 * 128;                    // 128*128
    P.SA    = (float*)(P.ANT + 128 * 128);           // 128*128 fp32 (scaled means)
    P.SU    = P.SA + 128 * 128;                      // 256*128 fp32 (half-batch colsums)

    hipMemsetAsync(P.cnt, 0, 256, stream);
    k_gnn<<<dim3(NBLK), dim3(256), 0, stream>>>(P);
}

// Round 5
// 227.696 us; speedup vs baseline: 1.4996x; 1.0292x over previous
//
#include <hip/hip_runtime.h>
#include <math.h>

// B=128, NU=32, NT=64, H=128, OUT_F=16, N_U=4096, N_A=8192
// Fully-bipartite-per-batch graph => segment-means are per-batch means.
// Single persistent kernel, 384 blocks x 256 threads, 5 grid barriers:
//  P0a: weight-prep, 13 slots x 8 k-slabs (104 blks; slot 12 = W_ue)
//  P0b: embed+colmean+ant (128 blks)
//  P1 : aggr it0 (128 hu-batch + 256 ha-half units; ha staged as ANT+noise)
//  P2 : comb it0 (256 ha units -> ha2, 128 hu units -> hu2)
//  P3 : aggr it1 (inputs hu2/ha2)
//  P4 : comb it1 ha-side + fused final normalize -> out
//
// Coherence protocol (R5): every cross-block buffer is written with sc1
// (write-through to MALL) stores and is WRITE-ONCE + first-touched by its
// readers only after the barrier (SA/SU double-buffered per iteration).
// Readers use normal cached loads: a never-cached line cannot be stale and
// MALL is memory-side coherent. Barrier = RELEASE add (wbl2 now ~free: no
// dirty cross-block lines) + RELAXED poll; NO acquire / buffer_inv at exit.
// R4's one-acquire-per-block (1536 full-L2 invalidates) left 141 us kernel
// at MfmaUtil 1.2% -- the invalidates thrashed blocks already in-phase.

using frag  = __attribute__((ext_vector_type(8))) short;   // 8 x bf16
using f32x4 = __attribute__((ext_vector_type(4))) float;
typedef unsigned u32x4 __attribute__((ext_vector_type(4)));
typedef unsigned u32x2 __attribute__((ext_vector_type(2)));

#define LDST 136          // 128 + 8 pad (272B rows: 16B-aligned, 2-way banks = free)
#define NBLK 384

__device__ __forceinline__ float  bf2f(ushort u) { return __uint_as_float(((unsigned)u) << 16); }
__device__ __forceinline__ ushort f2bf(float f) {
    unsigned u = __float_as_uint(f);
    u += 0x7fff + ((u >> 16) & 1);            // RNE
    return (ushort)(u >> 16);
}

// ---- sc1 write-through stores (visible at MALL without any L2 flush) ----
__device__ __forceinline__ void gst16_sc(void* p, u32x4 v) {
    asm volatile("global_store_dwordx4 %0, %1, off sc1" :: "v"(p), "v"(v) : "memory");
}
__device__ __forceinline__ void gst4_sc(void* p, unsigned v) {
    asm volatile("global_store_dword %0, %1, off sc1" :: "v"(p), "v"(v) : "memory");
}
__device__ __forceinline__ void gst2_sc(void* p, unsigned v) {
    asm volatile("global_store_short %0, %1, off sc1" :: "v"(p), "v"(v) : "memory");
}

struct GP {
    const float *uf, *noise, *b_ue, *W_t, *b_t;
    const float *wsrc[13];    // fp32 weights for prep; slot 12 = W_ue
    const float *bias6[6];    // ca_aggr_b, ca_self_b, ca_comb_b, cu_aggr_b, cu_self_b, cu_comb_b
    const float *Wn, *bn;
    float *out;
    ushort *WtAll, *hu, *hu2, *ha2, *ANT;
    float *SAa, *SUa, *SAb, *SUb;
    unsigned *cnt;
};
// WtAll slots: 0,1 ca_aggr L0/L1; 2,3 ca_self; 4,5 ca_comb; 6,7 cu_aggr;
//              8,9 cu_self; 10,11 cu_comb; 12 W_ue

// ---- grid barrier: RELEASE add, RELAXED poll, NO acquire at exit ----
__device__ __forceinline__ void gbar(unsigned* cnt, unsigned target) {
    __syncthreads();   // each wave drains vmcnt before s_barrier -> sc1 stores at MALL
    if (threadIdx.x == 0) {
        __hip_atomic_fetch_add(cnt, 1u, __ATOMIC_RELEASE, __HIP_MEMORY_SCOPE_AGENT);
        while (__hip_atomic_load(cnt, __ATOMIC_RELAXED, __HIP_MEMORY_SCOPE_AGENT) < target)
            __builtin_amdgcn_s_sleep(8);
    }
    __syncthreads();
}

// ---- one MLP stage on 32 rows: Y = relu(X @ W + b) (+ optional meanL add) ----
// Wt: global bf16 [n][k] (stride 128); A-frags L2-cached across blocks.
template<bool MEANADD>
__device__ __forceinline__ void mlp_stage(const ushort* Xl, ushort* Yl,
    const ushort* __restrict__ Wt, const float* __restrict__ bias, const float* meanL)
{
    const int lane = threadIdx.x & 63, wave = threadIdx.x >> 6;
    const int q = lane >> 4, l15 = lane & 15;
    frag A[2][4];
#pragma unroll
    for (int i = 0; i < 2; ++i) {
        const int n0 = (wave * 2 + i) * 16;
#pragma unroll
        for (int kc = 0; kc < 4; ++kc)
            A[i][kc] = *(const frag*)(Wt + (n0 + l15) * 128 + kc * 32 + q * 8);
    }
#pragma unroll
    for (int mt = 0; mt < 2; ++mt) {
        frag Bv[4];
#pragma unroll
        for (int kc = 0; kc < 4; ++kc)
            Bv[kc] = *(const frag*)(Xl + (mt * 16 + l15) * LDST + kc * 32 + q * 8);
#pragma unroll
        for (int i = 0; i < 2; ++i) {
            f32x4 acc = {0.f, 0.f, 0.f, 0.f};
#pragma unroll
            for (int kc = 0; kc < 4; ++kc)
                acc = __builtin_amdgcn_mfma_f32_16x16x32_bf16(A[i][kc], Bv[kc], acc, 0, 0, 0);
            const int n0 = (wave * 2 + i) * 16 + q * 4;
            const float4 bv = *(const float4*)(bias + n0);
            float v0 = acc[0] + bv.x, v1 = acc[1] + bv.y, v2 = acc[2] + bv.z, v3 = acc[3] + bv.w;
            v0 = v0 > 0.f ? v0 : 0.f; v1 = v1 > 0.f ? v1 : 0.f;
            v2 = v2 > 0.f ? v2 : 0.f; v3 = v3 > 0.f ? v3 : 0.f;
            if (MEANADD) {
                const float4 mv = *(const float4*)(meanL + n0);
                v0 += mv.x; v1 += mv.y; v2 += mv.z; v3 += mv.w;
            }
            ushort4 o = { f2bf(v0), f2bf(v1), f2bf(v2), f2bf(v3) };
            *(ushort4*)(Yl + (mt * 16 + l15) * LDST + n0) = o;
        }
    }
}

// ---- staging helpers (32 rows; cached loads) ----
__device__ __forceinline__ void stage_bf16_32(ushort* Xl, const ushort* __restrict__ src) {
    for (int c = threadIdx.x; c < 32 * 16; c += 256) {
        const int r = c >> 4, k8 = c & 15;
        *(uint4*)(Xl + r * LDST + k8 * 8) = *(const uint4*)(src + r * 128 + k8 * 8);
    }
}
__device__ __forceinline__ void stage_f32_32(ushort* Xl, const float* __restrict__ src) {
    for (int c = threadIdx.x; c < 32 * 32; c += 256) {
        const int r = c >> 5, k4 = c & 31;
        const float4 v = *(const float4*)(src + r * 128 + k4 * 4);
        ushort4 o = { f2bf(v.x), f2bf(v.y), f2bf(v.z), f2bf(v.w) };
        *(ushort4*)(Xl + r * LDST + k4 * 4) = o;
    }
}
__device__ __forceinline__ void stage_ha_32(ushort* Xl, const float* __restrict__ noise,
                                            const ushort* __restrict__ ant) {
    for (int c = threadIdx.x; c < 32 * 32; c += 256) {
        const int r = c >> 5, k4 = c & 31;
        const float4 v = *(const float4*)(noise + r * 128 + k4 * 4);
        const ushort4 a = *(const ushort4*)(ant + k4 * 4);
        ushort4 o = { f2bf(v.x + bf2f(a.x)), f2bf(v.y + bf2f(a.y)),
                      f2bf(v.z + bf2f(a.z)), f2bf(v.w + bf2f(a.w)) };
        *(ushort4*)(Xl + r * LDST + k4 * 4) = o;
    }
}
// write-through version: cross-block results
__device__ __forceinline__ void writeout_32_sc(ushort* __restrict__ dst, const ushort* Yl) {
    for (int c = threadIdx.x; c < 32 * 16; c += 256) {
        const int r = c >> 4, k8 = c & 15;
        gst16_sc(dst + r * 128 + k8 * 8, *(const u32x4*)(Yl + r * LDST + k8 * 8));
    }
}

// ---- weight transpose: fp32 [k][n] -> bf16 [n][k], one 16-k slab; sc1 out ----
__device__ __forceinline__ void wslab(ushort* dst, float* slab,
                                      const float* __restrict__ W, int kb)
{
    for (int c = threadIdx.x; c < 512; c += 256) {
        const int kr = c >> 5, c4 = c & 31;
        const float4 v = *(const float4*)(W + (kb * 16 + kr) * 128 + c4 * 4);
        slab[kr * 129 + c4 * 4 + 0] = v.x; slab[kr * 129 + c4 * 4 + 1] = v.y;
        slab[kr * 129 + c4 * 4 + 2] = v.z; slab[kr * 129 + c4 * 4 + 3] = v.w;
    }
    __syncthreads();
    for (int c = threadIdx.x; c < 1024; c += 256) {
        const int n = c >> 3, k2 = c & 7;
        const unsigned d = (unsigned)f2bf(slab[(2 * k2) * 129 + n])
                         | ((unsigned)f2bf(slab[(2 * k2 + 1) * 129 + n]) << 16);
        gst4_sc(dst + n * 128 + kb * 16 + 2 * k2, d);
    }
}

// ---- phase cores ----
__device__ __forceinline__ void aggr_core(ushort* buf0, ushort* buf1,
    const ushort* WtAll, int slot, const float* bias2, float* __restrict__ sumout, float scale)
{
    __syncthreads();
    mlp_stage<false>(buf0, buf1, WtAll + slot * 16384, bias2, nullptr);
    __syncthreads();
    mlp_stage<false>(buf1, buf0, WtAll + (slot + 1) * 16384, bias2 + 128, nullptr);
    __syncthreads();
    const int t = threadIdx.x;
    if (t < 128) {
        float s = 0.f;
        for (int r = 0; r < 32; ++r) s += bf2f(buf0[r * LDST + t]);
        gst4_sc(sumout + t, __float_as_uint(s * scale));
    }
}

template<bool FINAL>
__device__ __forceinline__ void comb_core(ushort* buf0, ushort* buf1, const float* meanL,
    const ushort* WtAll, int sslot, int cslot, const float* sbias, const float* cbias,
    ushort* __restrict__ dstg, const float* WnS, const float* __restrict__ bn,
    float* __restrict__ out, int r0)
{
    __syncthreads();
    mlp_stage<false>(buf0, buf1, WtAll + sslot * 16384, sbias, nullptr);
    __syncthreads();
    mlp_stage<true >(buf1, buf0, WtAll + (sslot + 1) * 16384, sbias + 128, meanL);
    __syncthreads();
    mlp_stage<false>(buf0, buf1, WtAll + cslot * 16384, cbias, nullptr);
    __syncthreads();
    mlp_stage<false>(buf1, buf0, WtAll + (cslot + 1) * 16384, cbias + 128, nullptr);
    __syncthreads();
    if (FINAL) {
        const int t = threadIdx.x, row = t >> 3, j = t & 7;
        float R = bn[j], I = bn[j + 8];
        const ushort* h = buf0 + row * LDST;
        for (int k = 0; k < 128; ++k) {
            const float hv = bf2f(h[k]);
            R += hv * WnS[k * 16 + j];
            I += hv * WnS[k * 16 + j + 8];
        }
        const float mag = sqrtf(R * R + I * I);
        const int a = r0 + row;
        out[a * 16 + j]     = R / mag;      // normal store: kernel-end flush covers host
        out[a * 16 + j + 8] = I / mag;
    } else {
        writeout_32_sc(dstg, buf0);
    }
}

__global__ __launch_bounds__(256, 2) void k_gnn(GP P)
{
    __shared__ __align__(16) ushort buf0[32 * LDST];
    __shared__ __align__(16) ushort buf1[32 * LDST];
    __shared__ __align__(16) float  WnS[128 * 16];
    __shared__ __align__(16) float  meanL[128];
    const int blk = blockIdx.x;
    const int tid = threadIdx.x;
    float* slab = (float*)buf0;   // 16x129 fp32 transpose temp (8256 B <= buf0)

    // ================= P0a: weight prep (13 slots x 8 slabs) =================
    if (blk < 104) {
        wslab(P.WtAll + (blk >> 3) * 16384, slab, P.wsrc[blk >> 3], blk & 7);
    }
    gbar(P.cnt, 1 * NBLK);

    // ================= P0b: embed + colmean + ant =================
    if (blk < 128) {
        const int b = blk;
        stage_f32_32(buf0, P.uf + (size_t)b * 32 * 128);
        __syncthreads();
        mlp_stage<false>(buf0, buf1, P.WtAll + 12 * 16384, P.b_ue, nullptr);
        __syncthreads();
        writeout_32_sc(P.hu + (size_t)b * 32 * 128, buf1);
        if (tid < 128) {                               // per-batch colmean (in LDS)
            float s = 0.f;
            for (int r = 0; r < 32; ++r) s += bf2f(buf1[r * LDST + tid]);
            meanL[tid] = s * (1.f / 32.f);
        }
        __syncthreads();
        if (tid < 128) {                               // ant[b] = relu(mean @ W_t + b_t), fp32
            float acc = P.b_t[tid];
            for (int k = 0; k < 128; ++k) acc += meanL[k] * P.W_t[k * 128 + tid];
            gst2_sc(P.ANT + b * 128 + tid, (unsigned)f2bf(acc > 0.f ? acc : 0.f));
        }
    }
    gbar(P.cnt, 2 * NBLK);

    // ================= P1: aggr it0 =================
    if (blk < 128) {             // msg = mlp2(hu[batch]) -> SAa[b] (mean, deg 32)
        stage_bf16_32(buf0, P.hu + (size_t)blk * 32 * 128);
        aggr_core(buf0, buf1, P.WtAll, 0, P.bias6[0], P.SAa + blk * 128, 1.f / 32.f);
    } else {                     // msg = mlp2(ha half-batch) -> SUa[v] (raw colsum)
        const int v = blk - 128;
        stage_ha_32(buf0, P.noise + (size_t)v * 32 * 128, P.ANT + (v >> 1) * 128);
        aggr_core(buf0, buf1, P.WtAll, 6, P.bias6[3], P.SUa + v * 128, 1.f);
    }
    gbar(P.cnt, 3 * NBLK);

    // ================= P2: comb it0 =================
    if (blk < 256) {             // na: 32 ha rows -> ha2
        const int r0 = blk * 32, b = blk >> 1;
        stage_ha_32(buf0, P.noise + (size_t)r0 * 128, P.ANT + b * 128);
        if (tid < 128) meanL[tid] = P.SAa[b * 128 + tid];
        comb_core<false>(buf0, buf1, meanL, P.WtAll, 2, 4, P.bias6[1], P.bias6[2],
                         P.ha2 + (size_t)r0 * 128, nullptr, nullptr, nullptr, 0);
    } else {                     // nu: 32 hu rows -> hu2
        const int b = blk - 256, r0 = b * 32;
        stage_bf16_32(buf0, P.hu + (size_t)r0 * 128);
        if (tid < 128)
            meanL[tid] = (P.SUa[(2 * b) * 128 + tid] + P.SUa[(2 * b + 1) * 128 + tid]) * (1.f / 64.f);
        comb_core<false>(buf0, buf1, meanL, P.WtAll, 8, 10, P.bias6[4], P.bias6[5],
                         P.hu2 + (size_t)r0 * 128, nullptr, nullptr, nullptr, 0);
    }
    gbar(P.cnt, 4 * NBLK);

    // ================= P3: aggr it1 (inputs hu2/ha2 -> SAb/SUb) =================
    if (blk < 128) {
        stage_bf16_32(buf0, P.hu2 + (size_t)blk * 32 * 128);
        aggr_core(buf0, buf1, P.WtAll, 0, P.bias6[0], P.SAb + blk * 128, 1.f / 32.f);
    } else {
        const int v = blk - 128;
        stage_bf16_32(buf0, P.ha2 + (size_t)v * 32 * 128);
        aggr_core(buf0, buf1, P.WtAll, 6, P.bias6[3], P.SUb + v * 128, 1.f);
    }
    gbar(P.cnt, 5 * NBLK);

    // ================= P4: comb it1 (ha only) + fused final =================
    if (blk < 256) {
        const int r0 = blk * 32, b = blk >> 1;
        stage_bf16_32(buf0, P.ha2 + (size_t)r0 * 128);
        for (int c = tid; c < 512; c += 256)
            *(float4*)(WnS + c * 4) = *(const float4*)(P.Wn + c * 4);
        if (tid < 128) meanL[tid] = P.SAb[b * 128 + tid];
        comb_core<true>(buf0, buf1, meanL, P.WtAll, 2, 4, P.bias6[1], P.bias6[2],
                        nullptr, WnS, P.bn, P.out, r0);
    }
}

extern "C" void kernel_launch(void* const* d_in, const int* in_sizes, int n_in,
                              void* d_out, int out_size, void* d_ws, size_t ws_size,
                              hipStream_t stream)
{
    GP P;
    P.uf    = (const float*)d_in[0];
    P.noise = (const float*)d_in[1];
    const float* W_ue = (const float*)d_in[6];
    P.b_ue  = (const float*)d_in[7];
    P.W_t   = (const float*)d_in[8];
    P.b_t   = (const float*)d_in[9];
    const float* caW[3] = {(const float*)d_in[10], (const float*)d_in[12], (const float*)d_in[14]};
    const float* cab[3] = {(const float*)d_in[11], (const float*)d_in[13], (const float*)d_in[15]};
    const float* cuW[3] = {(const float*)d_in[16], (const float*)d_in[18], (const float*)d_in[20]};
    const float* cub[3] = {(const float*)d_in[17], (const float*)d_in[19], (const float*)d_in[21]};
    P.Wn  = (const float*)d_in[22];
    P.bn  = (const float*)d_in[23];
    P.out = (float*)d_out;

    P.wsrc[0]  = caW[0]; P.wsrc[1]  = caW[0] + 16384;
    P.wsrc[2]  = caW[1]; P.wsrc[3]  = caW[1] + 16384;
    P.wsrc[4]  = caW[2]; P.wsrc[5]  = caW[2] + 16384;
    P.wsrc[6]  = cuW[0]; P.wsrc[7]  = cuW[0] + 16384;
    P.wsrc[8]  = cuW[1]; P.wsrc[9]  = cuW[1] + 16384;
    P.wsrc[10] = cuW[2]; P.wsrc[11] = cuW[2] + 16384;
    P.wsrc[12] = W_ue;
    P.bias6[0] = cab[0]; P.bias6[1] = cab[1]; P.bias6[2] = cab[2];
    P.bias6[3] = cub[0]; P.bias6[4] = cub[1]; P.bias6[5] = cub[2];

    char* w = (char*)d_ws;
    P.cnt   = (unsigned*)w;                          // 256 B reserved
    P.WtAll = (ushort*)(w + 256);                    // 13*16384 bf16
    P.hu    = P.WtAll + 13 * 16384;                  // 4096*128
    P.hu2   = P.hu  + 4096 * 128;
    P.ha2   = P.hu2 + 4096 * 128;                    // 8192*128
    P.ANT   = P.ha2 + 8192 * 128;                    // 128*128
    P.SAa   = (float*)(P.ANT + 128 * 128);           // 128*128 fp32
    P.SUa   = P.SAa + 128 * 128;                     // 256*128 fp32
    P.SAb   = P.SUa + 256 * 128;                     // 128*128 fp32
    P.SUb   = P.SAb + 128 * 128;                     // 256*128 fp32

    hipMemsetAsync(P.cnt, 0, 256, stream);
    k_gnn<<<dim3(NBLK), dim3(256), 0, stream>>>(P);
}

// Round 6
// 189.190 us; speedup vs baseline: 1.8048x; 1.2035x over previous
//
#include <hip/hip_runtime.h>
#include <math.h>

// B=128, NU=32, NT=64, H=128, OUT_F=16, N_U=4096, N_A=8192
// Fully-bipartite-per-batch graph => segment-means are per-batch means.
// Single persistent kernel, 384 blocks x 256 threads, 5 grid barriers:
//  P0a: weight-prep, 13 slots x 8 k-slabs (104 blks; slot 12 = W_ue)
//  P0b: embed+colmean+ant (128 blks)
//  P1 : aggr it0 (128 hu-batch + 256 ha-half units; ha staged as ANT+noise)
//  P2 : comb it0 (256 ha units -> ha2, 128 hu units -> hu2)
//  P3 : aggr it1 (inputs hu2/ha2)
//  P4 : comb it1 ha-side + fused final normalize -> out
//
// Coherence protocol: every cross-block buffer is written with sc1
// (write-through to MALL) stores, is WRITE-ONCE, and is first-touched by its
// readers only after the barrier (SA/SU double-buffered per iteration) -- a
// never-cached line cannot be stale, MALL is memory-side coherent.
//
// R6 change (the ONLY change vs R5): the barrier is maintenance-free.
//   R5: fetch_add(RELEASE, AGENT) -> lowered with buffer_wbl2 (full L2
//       writeback walk) per block per barrier; 48 serialized wbl2/XCD
//       ~= 25 us/barrier = the 125 us stall (MfmaUtil 1.2%).
//   R6: explicit per-wave s_waitcnt vmcnt(0) drain (sc1 stores are at MALL)
//       + __syncthreads rendezvous + RELAXED add + RELAXED poll. No wbl2,
//       no inv, anywhere. Per-phase counters 128 B apart.

using frag  = __attribute__((ext_vector_type(8))) short;   // 8 x bf16
using f32x4 = __attribute__((ext_vector_type(4))) float;
typedef unsigned u32x4 __attribute__((ext_vector_type(4)));

#define LDST 136          // 128 + 8 pad (272B rows: 16B-aligned, 2-way banks = free)
#define NBLK 384

__device__ __forceinline__ float  bf2f(ushort u) { return __uint_as_float(((unsigned)u) << 16); }
__device__ __forceinline__ ushort f2bf(float f) {
    unsigned u = __float_as_uint(f);
    u += 0x7fff + ((u >> 16) & 1);            // RNE
    return (ushort)(u >> 16);
}

// ---- sc1 write-through stores (visible at MALL without any L2 flush) ----
__device__ __forceinline__ void gst16_sc(void* p, u32x4 v) {
    asm volatile("global_store_dwordx4 %0, %1, off sc1" :: "v"(p), "v"(v) : "memory");
}
__device__ __forceinline__ void gst4_sc(void* p, unsigned v) {
    asm volatile("global_store_dword %0, %1, off sc1" :: "v"(p), "v"(v) : "memory");
}
__device__ __forceinline__ void gst2_sc(void* p, unsigned v) {
    asm volatile("global_store_short %0, %1, off sc1" :: "v"(p), "v"(v) : "memory");
}

struct GP {
    const float *uf, *noise, *b_ue, *W_t, *b_t;
    const float *wsrc[13];    // fp32 weights for prep; slot 12 = W_ue
    const float *bias6[6];    // ca_aggr_b, ca_self_b, ca_comb_b, cu_aggr_b, cu_self_b, cu_comb_b
    const float *Wn, *bn;
    float *out;
    ushort *WtAll, *hu, *hu2, *ha2, *ANT;
    float *SAa, *SUa, *SAb, *SUb;
    unsigned *cnt;            // per-phase counters, 32 u32 (128 B) apart
};
// WtAll slots: 0,1 ca_aggr L0/L1; 2,3 ca_self; 4,5 ca_comb; 6,7 cu_aggr;
//              8,9 cu_self; 10,11 cu_comb; 12 W_ue

// ---- grid barrier: vmcnt drain + RELAXED add + RELAXED poll. No wbl2/inv. ----
__device__ __forceinline__ void gbar(unsigned* c) {
    // each wave drains its own (inline-asm) sc1 stores to the MALL; the
    // compiler's waitcnt tracking does not cover asm stores.
    asm volatile("s_waitcnt vmcnt(0)" ::: "memory");
    __syncthreads();
    if (threadIdx.x == 0) {
        __hip_atomic_fetch_add(c, 1u, __ATOMIC_RELAXED, __HIP_MEMORY_SCOPE_AGENT);
        while (__hip_atomic_load(c, __ATOMIC_RELAXED, __HIP_MEMORY_SCOPE_AGENT) < NBLK)
            __builtin_amdgcn_s_sleep(8);
    }
    __syncthreads();   // also a compiler memory fence: no hoisting of phase loads
}

// ---- one MLP stage on 32 rows: Y = relu(X @ W + b) (+ optional meanL add) ----
// Wt: global bf16 [n][k] (stride 128); A-frags L2-cached across blocks (safe:
// weights are write-once in P0, read-only afterwards).
template<bool MEANADD>
__device__ __forceinline__ void mlp_stage(const ushort* Xl, ushort* Yl,
    const ushort* __restrict__ Wt, const float* __restrict__ bias, const float* meanL)
{
    const int lane = threadIdx.x & 63, wave = threadIdx.x >> 6;
    const int q = lane >> 4, l15 = lane & 15;
    frag A[2][4];
#pragma unroll
    for (int i = 0; i < 2; ++i) {
        const int n0 = (wave * 2 + i) * 16;
#pragma unroll
        for (int kc = 0; kc < 4; ++kc)
            A[i][kc] = *(const frag*)(Wt + (n0 + l15) * 128 + kc * 32 + q * 8);
    }
#pragma unroll
    for (int mt = 0; mt < 2; ++mt) {
        frag Bv[4];
#pragma unroll
        for (int kc = 0; kc < 4; ++kc)
            Bv[kc] = *(const frag*)(Xl + (mt * 16 + l15) * LDST + kc * 32 + q * 8);
#pragma unroll
        for (int i = 0; i < 2; ++i) {
            f32x4 acc = {0.f, 0.f, 0.f, 0.f};
#pragma unroll
            for (int kc = 0; kc < 4; ++kc)
                acc = __builtin_amdgcn_mfma_f32_16x16x32_bf16(A[i][kc], Bv[kc], acc, 0, 0, 0);
            const int n0 = (wave * 2 + i) * 16 + q * 4;
            const float4 bv = *(const float4*)(bias + n0);
            float v0 = acc[0] + bv.x, v1 = acc[1] + bv.y, v2 = acc[2] + bv.z, v3 = acc[3] + bv.w;
            v0 = v0 > 0.f ? v0 : 0.f; v1 = v1 > 0.f ? v1 : 0.f;
            v2 = v2 > 0.f ? v2 : 0.f; v3 = v3 > 0.f ? v3 : 0.f;
            if (MEANADD) {
                const float4 mv = *(const float4*)(meanL + n0);
                v0 += mv.x; v1 += mv.y; v2 += mv.z; v3 += mv.w;
            }
            ushort4 o = { f2bf(v0), f2bf(v1), f2bf(v2), f2bf(v3) };
            *(ushort4*)(Yl + (mt * 16 + l15) * LDST + n0) = o;
        }
    }
}

// ---- staging helpers (32 rows; cached loads) ----
__device__ __forceinline__ void stage_bf16_32(ushort* Xl, const ushort* __restrict__ src) {
    for (int c = threadIdx.x; c < 32 * 16; c += 256) {
        const int r = c >> 4, k8 = c & 15;
        *(uint4*)(Xl + r * LDST + k8 * 8) = *(const uint4*)(src + r * 128 + k8 * 8);
    }
}
__device__ __forceinline__ void stage_f32_32(ushort* Xl, const float* __restrict__ src) {
    for (int c = threadIdx.x; c < 32 * 32; c += 256) {
        const int r = c >> 5, k4 = c & 31;
        const float4 v = *(const float4*)(src + r * 128 + k4 * 4);
        ushort4 o = { f2bf(v.x), f2bf(v.y), f2bf(v.z), f2bf(v.w) };
        *(ushort4*)(Xl + r * LDST + k4 * 4) = o;
    }
}
__device__ __forceinline__ void stage_ha_32(ushort* Xl, const float* __restrict__ noise,
                                            const ushort* __restrict__ ant) {
    for (int c = threadIdx.x; c < 32 * 32; c += 256) {
        const int r = c >> 5, k4 = c & 31;
        const float4 v = *(const float4*)(noise + r * 128 + k4 * 4);
        const ushort4 a = *(const ushort4*)(ant + k4 * 4);
        ushort4 o = { f2bf(v.x + bf2f(a.x)), f2bf(v.y + bf2f(a.y)),
                      f2bf(v.z + bf2f(a.z)), f2bf(v.w + bf2f(a.w)) };
        *(ushort4*)(Xl + r * LDST + k4 * 4) = o;
    }
}
// write-through version: cross-block results
__device__ __forceinline__ void writeout_32_sc(ushort* __restrict__ dst, const ushort* Yl) {
    for (int c = threadIdx.x; c < 32 * 16; c += 256) {
        const int r = c >> 4, k8 = c & 15;
        gst16_sc(dst + r * 128 + k8 * 8, *(const u32x4*)(Yl + r * LDST + k8 * 8));
    }
}

// ---- weight transpose: fp32 [k][n] -> bf16 [n][k], one 16-k slab; sc1 out ----
__device__ __forceinline__ void wslab(ushort* dst, float* slab,
                                      const float* __restrict__ W, int kb)
{
    for (int c = threadIdx.x; c < 512; c += 256) {
        const int kr = c >> 5, c4 = c & 31;
        const float4 v = *(const float4*)(W + (kb * 16 + kr) * 128 + c4 * 4);
        slab[kr * 129 + c4 * 4 + 0] = v.x; slab[kr * 129 + c4 * 4 + 1] = v.y;
        slab[kr * 129 + c4 * 4 + 2] = v.z; slab[kr * 129 + c4 * 4 + 3] = v.w;
    }
    __syncthreads();
    for (int c = threadIdx.x; c < 1024; c += 256) {
        const int n = c >> 3, k2 = c & 7;
        const unsigned d = (unsigned)f2bf(slab[(2 * k2) * 129 + n])
                         | ((unsigned)f2bf(slab[(2 * k2 + 1) * 129 + n]) << 16);
        gst4_sc(dst + n * 128 + kb * 16 + 2 * k2, d);
    }
}

// ---- phase cores ----
__device__ __forceinline__ void aggr_core(ushort* buf0, ushort* buf1,
    const ushort* WtAll, int slot, const float* bias2, float* __restrict__ sumout, float scale)
{
    __syncthreads();
    mlp_stage<false>(buf0, buf1, WtAll + slot * 16384, bias2, nullptr);
    __syncthreads();
    mlp_stage<false>(buf1, buf0, WtAll + (slot + 1) * 16384, bias2 + 128, nullptr);
    __syncthreads();
    const int t = threadIdx.x;
    if (t < 128) {
        float s = 0.f;
        for (int r = 0; r < 32; ++r) s += bf2f(buf0[r * LDST + t]);
        gst4_sc(sumout + t, __float_as_uint(s * scale));
    }
}

template<bool FINAL>
__device__ __forceinline__ void comb_core(ushort* buf0, ushort* buf1, const float* meanL,
    const ushort* WtAll, int sslot, int cslot, const float* sbias, const float* cbias,
    ushort* __restrict__ dstg, const float* WnS, const float* __restrict__ bn,
    float* __restrict__ out, int r0)
{
    __syncthreads();
    mlp_stage<false>(buf0, buf1, WtAll + sslot * 16384, sbias, nullptr);
    __syncthreads();
    mlp_stage<true >(buf1, buf0, WtAll + (sslot + 1) * 16384, sbias + 128, meanL);
    __syncthreads();
    mlp_stage<false>(buf0, buf1, WtAll + cslot * 16384, cbias, nullptr);
    __syncthreads();
    mlp_stage<false>(buf1, buf0, WtAll + (cslot + 1) * 16384, cbias + 128, nullptr);
    __syncthreads();
    if (FINAL) {
        const int t = threadIdx.x, row = t >> 3, j = t & 7;
        float R = bn[j], I = bn[j + 8];
        const ushort* h = buf0 + row * LDST;
        for (int k = 0; k < 128; ++k) {
            const float hv = bf2f(h[k]);
            R += hv * WnS[k * 16 + j];
            I += hv * WnS[k * 16 + j + 8];
        }
        const float mag = sqrtf(R * R + I * I);
        const int a = r0 + row;
        out[a * 16 + j]     = R / mag;      // normal store: kernel-end flush covers host
        out[a * 16 + j + 8] = I / mag;
    } else {
        writeout_32_sc(dstg, buf0);
    }
}

__global__ __launch_bounds__(256, 2) void k_gnn(GP P)
{
    __shared__ __align__(16) ushort buf0[32 * LDST];
    __shared__ __align__(16) ushort buf1[32 * LDST];
    __shared__ __align__(16) float  WnS[128 * 16];
    __shared__ __align__(16) float  meanL[128];
    const int blk = blockIdx.x;
    const int tid = threadIdx.x;
    float* slab = (float*)buf0;   // 16x129 fp32 transpose temp (8256 B <= buf0)

    // ================= P0a: weight prep (13 slots x 8 slabs) =================
    if (blk < 104) {
        wslab(P.WtAll + (blk >> 3) * 16384, slab, P.wsrc[blk >> 3], blk & 7);
    }
    gbar(P.cnt + 0 * 32);

    // ================= P0b: embed + colmean + ant =================
    if (blk < 128) {
        const int b = blk;
        stage_f32_32(buf0, P.uf + (size_t)b * 32 * 128);
        __syncthreads();
        mlp_stage<false>(buf0, buf1, P.WtAll + 12 * 16384, P.b_ue, nullptr);
        __syncthreads();
        writeout_32_sc(P.hu + (size_t)b * 32 * 128, buf1);
        if (tid < 128) {                               // per-batch colmean (in LDS)
            float s = 0.f;
            for (int r = 0; r < 32; ++r) s += bf2f(buf1[r * LDST + tid]);
            meanL[tid] = s * (1.f / 32.f);
        }
        __syncthreads();
        if (tid < 128) {                               // ant[b] = relu(mean @ W_t + b_t), fp32
            float acc = P.b_t[tid];
            for (int k = 0; k < 128; ++k) acc += meanL[k] * P.W_t[k * 128 + tid];
            gst2_sc(P.ANT + b * 128 + tid, (unsigned)f2bf(acc > 0.f ? acc : 0.f));
        }
    }
    gbar(P.cnt + 1 * 32);

    // ================= P1: aggr it0 =================
    if (blk < 128) {             // msg = mlp2(hu[batch]) -> SAa[b] (mean, deg 32)
        stage_bf16_32(buf0, P.hu + (size_t)blk * 32 * 128);
        aggr_core(buf0, buf1, P.WtAll, 0, P.bias6[0], P.SAa + blk * 128, 1.f / 32.f);
    } else {                     // msg = mlp2(ha half-batch) -> SUa[v] (raw colsum)
        const int v = blk - 128;
        stage_ha_32(buf0, P.noise + (size_t)v * 32 * 128, P.ANT + (v >> 1) * 128);
        aggr_core(buf0, buf1, P.WtAll, 6, P.bias6[3], P.SUa + v * 128, 1.f);
    }
    gbar(P.cnt + 2 * 32);

    // ================= P2: comb it0 =================
    if (blk < 256) {             // na: 32 ha rows -> ha2
        const int r0 = blk * 32, b = blk >> 1;
        stage_ha_32(buf0, P.noise + (size_t)r0 * 128, P.ANT + b * 128);
        if (tid < 128) meanL[tid] = P.SAa[b * 128 + tid];
        comb_core<false>(buf0, buf1, meanL, P.WtAll, 2, 4, P.bias6[1], P.bias6[2],
                         P.ha2 + (size_t)r0 * 128, nullptr, nullptr, nullptr, 0);
    } else {                     // nu: 32 hu rows -> hu2
        const int b = blk - 256, r0 = b * 32;
        stage_bf16_32(buf0, P.hu + (size_t)r0 * 128);
        if (tid < 128)
            meanL[tid] = (P.SUa[(2 * b) * 128 + tid] + P.SUa[(2 * b + 1) * 128 + tid]) * (1.f / 64.f);
        comb_core<false>(buf0, buf1, meanL, P.WtAll, 8, 10, P.bias6[4], P.bias6[5],
                         P.hu2 + (size_t)r0 * 128, nullptr, nullptr, nullptr, 0);
    }
    gbar(P.cnt + 3 * 32);

    // ================= P3: aggr it1 (inputs hu2/ha2 -> SAb/SUb) =================
    if (blk < 128) {
        stage_bf16_32(buf0, P.hu2 + (size_t)blk * 32 * 128);
        aggr_core(buf0, buf1, P.WtAll, 0, P.bias6[0], P.SAb + blk * 128, 1.f / 32.f);
    } else {
        const int v = blk - 128;
        stage_bf16_32(buf0, P.ha2 + (size_t)v * 32 * 128);
        aggr_core(buf0, buf1, P.WtAll, 6, P.bias6[3], P.SUb + v * 128, 1.f);
    }
    gbar(P.cnt + 4 * 32);

    // ================= P4: comb it1 (ha only) + fused final =================
    if (blk < 256) {
        const int r0 = blk * 32, b = blk >> 1;
        stage_bf16_32(buf0, P.ha2 + (size_t)r0 * 128);
        for (int c = tid; c < 512; c += 256)
            *(float4*)(WnS + c * 4) = *(const float4*)(P.Wn + c * 4);
        if (tid < 128) meanL[tid] = P.SAb[b * 128 + tid];
        comb_core<true>(buf0, buf1, meanL, P.WtAll, 2, 4, P.bias6[1], P.bias6[2],
                        nullptr, WnS, P.bn, P.out, r0);
    }
}

extern "C" void kernel_launch(void* const* d_in, const int* in_sizes, int n_in,
                              void* d_out, int out_size, void* d_ws, size_t ws_size,
                              hipStream_t stream)
{
    GP P;
    P.uf    = (const float*)d_in[0];
    P.noise = (const float*)d_in[1];
    const float* W_ue = (const float*)d_in[6];
    P.b_ue  = (const float*)d_in[7];
    P.W_t   = (const float*)d_in[8];
    P.b_t   = (const float*)d_in[9];
    const float* caW[3] = {(const float*)d_in[10], (const float*)d_in[12], (const float*)d_in[14]};
    const float* cab[3] = {(const float*)d_in[11], (const float*)d_in[13], (const float*)d_in[15]};
    const float* cuW[3] = {(const float*)d_in[16], (const float*)d_in[18], (const float*)d_in[20]};
    const float* cub[3] = {(const float*)d_in[17], (const float*)d_in[19], (const float*)d_in[21]};
    P.Wn  = (const float*)d_in[22];
    P.bn  = (const float*)d_in[23];
    P.out = (float*)d_out;

    P.wsrc[0]  = caW[0]; P.wsrc[1]  = caW[0] + 16384;
    P.wsrc[2]  = caW[1]; P.wsrc[3]  = caW[1] + 16384;
    P.wsrc[4]  = caW[2]; P.wsrc[5]  = caW[2] + 16384;
    P.wsrc[6]  = cuW[0]; P.wsrc[7]  = cuW[0] + 16384;
    P.wsrc[8]  = cuW[1]; P.wsrc[9]  = cuW[1] + 16384;
    P.wsrc[10] = cuW[2]; P.wsrc[11] = cuW[2] + 16384;
    P.wsrc[12] = W_ue;
    P.bias6[0] = cab[0]; P.bias6[1] = cab[1]; P.bias6[2] = cab[2];
    P.bias6[3] = cub[0]; P.bias6[4] = cub[1]; P.bias6[5] = cub[2];

    char* w = (char*)d_ws;
    P.cnt   = (unsigned*)w;                          // 5 counters, 128 B apart (1024 B reserved)
    P.WtAll = (ushort*)(w + 1024);                   // 13*16384 bf16
    P.hu    = P.WtAll + 13 * 16384;                  // 4096*128
    P.hu2   = P.hu  + 4096 * 128;
    P.ha2   = P.hu2 + 4096 * 128;                    // 8192*128
    P.ANT   = P.ha2 + 8192 * 128;                    // 128*128
    P.SAa   = (float*)(P.ANT + 128 * 128);           // 128*128 fp32
    P.SUa   = P.SAa + 128 * 128;                     // 256*128 fp32
    P.SAb   = P.SUa + 256 * 128;                     // 128*128 fp32
    P.SUb   = P.SAb + 128 * 128;                     // 256*128 fp32

    hipMemsetAsync(P.cnt, 0, 1024, stream);
    k_gnn<<<dim3(NBLK), dim3(256), 0, stream>>>(P);
}

// Round 7
// 149.645 us; speedup vs baseline: 2.2817x; 1.2643x over previous
//
#include <hip/hip_runtime.h>
#include <math.h>

// B=128, NU=32, NT=64, H=128, OUT_F=16, N_U=4096, N_A=8192
// KEY STRUCTURE (R7): the graph is fully-bipartite WITHIN each batch and all
// reductions (ant-mean, segment-means) are per-batch => the entire 2-iteration
// GNN decomposes into 128 independent per-batch programs sharing only the
// weights. Grid sync is needed once (weight prep). Everything else syncs
// pairwise between the 2 blocks of a batch.
//
// 256 blocks x 256 threads: block (b,half) owns 16 hu rows + 32 ha rows.
// All activations live in LDS end-to-end. Cross-block data = 5 x 512B column
// -sum partials per block (write-once, sc1 write-through, first-touched by
// the partner only after a seq-flag sync) + 3 pairwise syncs + 1 flag-based
// prep barrier (fetch_add detects last arriver; everyone polls a read-only
// flag line => no RMW/poll contention on one MALL slice, R6's ~17us/barrier).
//
// GEMMs: bf16 MFMA 16x16x32, Y^T = W^T X^T; weights pre-transposed to [n][k].

using frag  = __attribute__((ext_vector_type(8))) short;   // 8 x bf16
using f32x4 = __attribute__((ext_vector_type(4))) float;

#define LDST 136    // 128 + 8 pad
#define SCOPE_AGT __HIP_MEMORY_SCOPE_AGENT

__device__ __forceinline__ float  bf2f(ushort u) { return __uint_as_float(((unsigned)u) << 16); }
__device__ __forceinline__ ushort f2bf(float f) {
    unsigned u = __float_as_uint(f);
    u += 0x7fff + ((u >> 16) & 1);            // RNE
    return (ushort)(u >> 16);
}
__device__ __forceinline__ void gst4_sc(void* p, unsigned v) {   // write-through to MALL
    asm volatile("global_store_dword %0, %1, off sc1" :: "v"(p), "v"(v) : "memory");
}

struct GP {
    const float *uf, *noise, *b_ue, *W_t, *b_t;
    const float *wsrc[13];    // fp32 weight mats for prep; slot 12 = W_ue
    const float *bias6[6];    // ca_aggr_b, ca_self_b, ca_comb_b, cu_aggr_b, cu_self_b, cu_comb_b
    const float *Wn, *bn;
    float *out;
    ushort *WtAll;            // 13 x [128][128] bf16 (n-major)
    float *pE, *pA0, *pU0, *pA1, *pU1;   // per-block 128-f column-sum partials
    unsigned *cnt, *flg;      // prep counter/flag; per-block pair flags (128B apart)
};
// WtAll slots: 0,1 ca_aggr; 2,3 ca_self; 4,5 ca_comb; 6,7 cu_aggr;
//              8,9 cu_self; 10,11 cu_comb; 12 W_ue

// ---- pairwise sync: single-writer seq flags, no atomics RMW ----
__device__ __forceinline__ void psync(unsigned* myf, unsigned* pf, unsigned s) {
    asm volatile("s_waitcnt vmcnt(0)" ::: "memory");   // drain my sc1 partial stores
    __syncthreads();
    if (threadIdx.x == 0) {
        __hip_atomic_store(myf, s, __ATOMIC_RELAXED, SCOPE_AGT);
        while (__hip_atomic_load(pf, __ATOMIC_RELAXED, SCOPE_AGT) < s)
            __builtin_amdgcn_s_sleep(2);
    }
    __syncthreads();
}

// ---- one MLP stage: Y = relu(X @ W + b) (+ optional meanL add), MT m-tiles ----
template<int MT, bool MEANADD>
__device__ __forceinline__ void mlp_stage(const ushort* Xl, ushort* Yl,
    const ushort* __restrict__ Wt, const float* __restrict__ bias, const float* meanL)
{
    const int lane = threadIdx.x & 63, wave = threadIdx.x >> 6;
    const int q = lane >> 4, l15 = lane & 15;
    frag A[2][4];
#pragma unroll
    for (int i = 0; i < 2; ++i) {
        const int n0 = (wave * 2 + i) * 16;
#pragma unroll
        for (int kc = 0; kc < 4; ++kc)
            A[i][kc] = *(const frag*)(Wt + (n0 + l15) * 128 + kc * 32 + q * 8);
    }
#pragma unroll
    for (int mt = 0; mt < MT; ++mt) {
        frag Bv[4];
#pragma unroll
        for (int kc = 0; kc < 4; ++kc)
            Bv[kc] = *(const frag*)(Xl + (mt * 16 + l15) * LDST + kc * 32 + q * 8);
#pragma unroll
        for (int i = 0; i < 2; ++i) {
            f32x4 acc = {0.f, 0.f, 0.f, 0.f};
#pragma unroll
            for (int kc = 0; kc < 4; ++kc)
                acc = __builtin_amdgcn_mfma_f32_16x16x32_bf16(A[i][kc], Bv[kc], acc, 0, 0, 0);
            const int n0 = (wave * 2 + i) * 16 + q * 4;
            const float4 bv = *(const float4*)(bias + n0);
            float v0 = acc[0] + bv.x, v1 = acc[1] + bv.y, v2 = acc[2] + bv.z, v3 = acc[3] + bv.w;
            v0 = v0 > 0.f ? v0 : 0.f; v1 = v1 > 0.f ? v1 : 0.f;
            v2 = v2 > 0.f ? v2 : 0.f; v3 = v3 > 0.f ? v3 : 0.f;
            if (MEANADD) {
                const float4 mv = *(const float4*)(meanL + n0);
                v0 += mv.x; v1 += mv.y; v2 += mv.z; v3 += mv.w;
            }
            ushort4 o = { f2bf(v0), f2bf(v1), f2bf(v2), f2bf(v3) };
            *(ushort4*)(Yl + (mt * 16 + l15) * LDST + n0) = o;
        }
    }
}

__device__ __forceinline__ void colsum_sc(const ushort* buf, int rows, float* __restrict__ dst) {
    const int t = threadIdx.x;
    if (t < 128) {
        float s = 0.f;
        for (int r = 0; r < rows; ++r) s += bf2f(buf[r * LDST + t]);
        gst4_sc(dst + t, __float_as_uint(s));
    }
}

// ---- weight transpose: fp32 [k][n] -> bf16 [n][k], one 16-k slab; sc1 out ----
__device__ __forceinline__ void wslab(ushort* dst, float* slab,
                                      const float* __restrict__ W, int kb)
{
    for (int c = threadIdx.x; c < 512; c += 256) {
        const int kr = c >> 5, c4 = c & 31;
        const float4 v = *(const float4*)(W + (kb * 16 + kr) * 128 + c4 * 4);
        slab[kr * 129 + c4 * 4 + 0] = v.x; slab[kr * 129 + c4 * 4 + 1] = v.y;
        slab[kr * 129 + c4 * 4 + 2] = v.z; slab[kr * 129 + c4 * 4 + 3] = v.w;
    }
    __syncthreads();
    for (int c = threadIdx.x; c < 1024; c += 256) {
        const int n = c >> 3, k2 = c & 7;
        const unsigned d = (unsigned)f2bf(slab[(2 * k2) * 129 + n])
                         | ((unsigned)f2bf(slab[(2 * k2 + 1) * 129 + n]) << 16);
        gst4_sc(dst + n * 128 + kb * 16 + 2 * k2, d);
    }
    __syncthreads();
}

__global__ __launch_bounds__(256, 1) void k_gnn(GP P)
{
    __shared__ __align__(16) ushort HU [16 * LDST];   // own hu rows
    __shared__ __align__(16) ushort HU2[16 * LDST];
    __shared__ __align__(16) ushort HA [32 * LDST];   // own ha rows
    __shared__ __align__(16) ushort HA2[32 * LDST];
    __shared__ __align__(16) ushort T0 [32 * LDST];
    __shared__ __align__(16) ushort T1 [32 * LDST];
    __shared__ float meanL[128];
    __shared__ float antL[128];

    const int blk = blockIdx.x, tid = threadIdx.x;
    const int b = blk >> 1, half = blk & 1;
    unsigned* myf = P.flg + blk * 32;
    unsigned* prf = P.flg + (blk ^ 1) * 32;
    const ushort* Wt = P.WtAll;

    // ---- weight prep (104 of 256 blocks; slab temp in T1) ----
    if (blk < 104)
        wslab(P.WtAll + (blk >> 3) * 16384, (float*)T1, P.wsrc[blk >> 3], blk & 7);

    // stage own 16 uf rows (input data: no coherence concern) -> T0
    for (int c = tid; c < 16 * 32; c += 256) {
        const int r = c >> 5, k4 = c & 31;
        const float4 v = *(const float4*)(P.uf + (size_t)(b * 32 + half * 16 + r) * 128 + k4 * 4);
        ushort4 o = { f2bf(v.x), f2bf(v.y), f2bf(v.z), f2bf(v.w) };
        *(ushort4*)(T0 + r * LDST + k4 * 4) = o;
    }

    // ---- global prep barrier: last arriver broadcasts a flag ----
    asm volatile("s_waitcnt vmcnt(0)" ::: "memory");
    __syncthreads();
    if (tid == 0) {
        if (blk < 104) {
            unsigned old = __hip_atomic_fetch_add(P.cnt, 1u, __ATOMIC_RELAXED, SCOPE_AGT);
            if (old == 103u) __hip_atomic_store(P.cnt + 32, 1u, __ATOMIC_RELAXED, SCOPE_AGT);
        }
        while (__hip_atomic_load(P.cnt + 32, __ATOMIC_RELAXED, SCOPE_AGT) < 1u)
            __builtin_amdgcn_s_sleep(8);
    }
    __syncthreads();

    // ---- embed own 16 rows; exchange colsums; ant (redundant per half) ----
    mlp_stage<1, false>(T0, HU, Wt + 12 * 16384, P.b_ue, nullptr);
    __syncthreads();
    colsum_sc(HU, 16, P.pE + blk * 128);
    psync(myf, prf, 1u);
    if (tid < 128)
        meanL[tid] = (P.pE[blk * 128 + tid] + P.pE[(blk ^ 1) * 128 + tid]) * (1.f / 32.f);
    __syncthreads();
    if (tid < 128) {
        float acc = P.b_t[tid];
#pragma unroll 4
        for (int k = 0; k < 128; ++k) acc += meanL[k] * P.W_t[k * 128 + tid];
        antL[tid] = acc > 0.f ? acc : 0.f;
    }
    __syncthreads();
    // stage own 32 ha rows = ant + noise
    for (int c = tid; c < 32 * 32; c += 256) {
        const int r = c >> 5, k4 = c & 31;
        const float4 v = *(const float4*)(P.noise + (size_t)(b * 64 + half * 32 + r) * 128 + k4 * 4);
        ushort4 o = { f2bf(v.x + antL[k4 * 4 + 0]), f2bf(v.y + antL[k4 * 4 + 1]),
                      f2bf(v.z + antL[k4 * 4 + 2]), f2bf(v.w + antL[k4 * 4 + 3]) };
        *(ushort4*)(HA + r * LDST + k4 * 4) = o;
    }
    __syncthreads();

    // ---- it0 aggr: msgs from hu (ca_aggr) and ha (cu_aggr); exchange sums ----
    mlp_stage<1, false>(HU, T0, Wt + 0 * 16384, P.bias6[0], nullptr);
    __syncthreads();
    mlp_stage<1, false>(T0, T1, Wt + 1 * 16384, P.bias6[0] + 128, nullptr);
    __syncthreads();
    colsum_sc(T1, 16, P.pA0 + blk * 128);
    __syncthreads();
    mlp_stage<2, false>(HA, T0, Wt + 6 * 16384, P.bias6[3], nullptr);
    __syncthreads();
    mlp_stage<2, false>(T0, T1, Wt + 7 * 16384, P.bias6[3] + 128, nullptr);
    __syncthreads();
    colsum_sc(T1, 32, P.pU0 + blk * 128);
    psync(myf, prf, 2u);

    // ---- it0 comb: ha2 = comb(self(ha)+meanA); hu2 = comb(self(hu)+meanU) ----
    if (tid < 128)
        meanL[tid] = (P.pA0[blk * 128 + tid] + P.pA0[(blk ^ 1) * 128 + tid]) * (1.f / 32.f);
    __syncthreads();
    mlp_stage<2, false>(HA, T0, Wt + 2 * 16384, P.bias6[1], nullptr);
    __syncthreads();
    mlp_stage<2, true >(T0, T1, Wt + 3 * 16384, P.bias6[1] + 128, meanL);
    __syncthreads();
    mlp_stage<2, false>(T1, T0, Wt + 4 * 16384, P.bias6[2], nullptr);
    __syncthreads();
    mlp_stage<2, false>(T0, HA2, Wt + 5 * 16384, P.bias6[2] + 128, nullptr);
    __syncthreads();
    if (tid < 128)
        meanL[tid] = (P.pU0[blk * 128 + tid] + P.pU0[(blk ^ 1) * 128 + tid]) * (1.f / 64.f);
    __syncthreads();
    mlp_stage<1, false>(HU, T0, Wt + 8 * 16384, P.bias6[4], nullptr);
    __syncthreads();
    mlp_stage<1, true >(T0, T1, Wt + 9 * 16384, P.bias6[4] + 128, meanL);
    __syncthreads();
    mlp_stage<1, false>(T1, T0, Wt + 10 * 16384, P.bias6[5], nullptr);
    __syncthreads();
    mlp_stage<1, false>(T0, HU2, Wt + 11 * 16384, P.bias6[5] + 128, nullptr);
    __syncthreads();

    // ---- it1 aggr (on hu2/ha2); exchange sums ----
    mlp_stage<1, false>(HU2, T0, Wt + 0 * 16384, P.bias6[0], nullptr);
    __syncthreads();
    mlp_stage<1, false>(T0, T1, Wt + 1 * 16384, P.bias6[0] + 128, nullptr);
    __syncthreads();
    colsum_sc(T1, 16, P.pA1 + blk * 128);
    __syncthreads();
    mlp_stage<2, false>(HA2, T0, Wt + 6 * 16384, P.bias6[3], nullptr);
    __syncthreads();
    mlp_stage<2, false>(T0, T1, Wt + 7 * 16384, P.bias6[3] + 128, nullptr);
    __syncthreads();
    colsum_sc(T1, 32, P.pU1 + blk * 128);
    psync(myf, prf, 3u);

    // ---- it1 comb (ha side only; hu2' is dead) + fused final normalize ----
    if (tid < 128)
        meanL[tid] = (P.pA1[blk * 128 + tid] + P.pA1[(blk ^ 1) * 128 + tid]) * (1.f / 32.f);
    __syncthreads();
    mlp_stage<2, false>(HA2, T0, Wt + 2 * 16384, P.bias6[1], nullptr);
    __syncthreads();
    mlp_stage<2, true >(T0, T1, Wt + 3 * 16384, P.bias6[1] + 128, meanL);
    __syncthreads();
    mlp_stage<2, false>(T1, T0, Wt + 4 * 16384, P.bias6[2], nullptr);
    __syncthreads();
    mlp_stage<2, false>(T0, T1, Wt + 5 * 16384, P.bias6[2] + 128, nullptr);
    __syncthreads();
    float* WnS = (float*)T0;                       // 8 KB <= T0
    for (int c = tid; c < 512; c += 256)
        *(float4*)(WnS + c * 4) = *(const float4*)(P.Wn + c * 4);
    __syncthreads();
    {
        const int row = tid >> 3, j = tid & 7;     // 32 rows x 8 cols
        float R = P.bn[j], I = P.bn[j + 8];
        const ushort* h = T1 + row * LDST;
        for (int k = 0; k < 128; ++k) {
            const float hv = bf2f(h[k]);
            R += hv * WnS[k * 16 + j];
            I += hv * WnS[k * 16 + j + 8];
        }
        const float mag = sqrtf(R * R + I * I);
        const int a = b * 64 + half * 32 + row;
        P.out[a * 16 + j]     = R / mag;
        P.out[a * 16 + j + 8] = I / mag;
    }
}

extern "C" void kernel_launch(void* const* d_in, const int* in_sizes, int n_in,
                              void* d_out, int out_size, void* d_ws, size_t ws_size,
                              hipStream_t stream)
{
    GP P;
    P.uf    = (const float*)d_in[0];
    P.noise = (const float*)d_in[1];
    const float* W_ue = (const float*)d_in[6];
    P.b_ue  = (const float*)d_in[7];
    P.W_t   = (const float*)d_in[8];
    P.b_t   = (const float*)d_in[9];
    const float* caW[3] = {(const float*)d_in[10], (const float*)d_in[12], (const float*)d_in[14]};
    const float* cab[3] = {(const float*)d_in[11], (const float*)d_in[13], (const float*)d_in[15]};
    const float* cuW[3] = {(const float*)d_in[16], (const float*)d_in[18], (const float*)d_in[20]};
    const float* cub[3] = {(const float*)d_in[17], (const float*)d_in[19], (const float*)d_in[21]};
    P.Wn  = (const float*)d_in[22];
    P.bn  = (const float*)d_in[23];
    P.out = (float*)d_out;

    P.wsrc[0]  = caW[0]; P.wsrc[1]  = caW[0] + 16384;
    P.wsrc[2]  = caW[1]; P.wsrc[3]  = caW[1] + 16384;
    P.wsrc[4]  = caW[2]; P.wsrc[5]  = caW[2] + 16384;
    P.wsrc[6]  = cuW[0]; P.wsrc[7]  = cuW[0] + 16384;
    P.wsrc[8]  = cuW[1]; P.wsrc[9]  = cuW[1] + 16384;
    P.wsrc[10] = cuW[2]; P.wsrc[11] = cuW[2] + 16384;
    P.wsrc[12] = W_ue;
    P.bias6[0] = cab[0]; P.bias6[1] = cab[1]; P.bias6[2] = cab[2];
    P.bias6[3] = cub[0]; P.bias6[4] = cub[1]; P.bias6[5] = cub[2];

    char* w = (char*)d_ws;
    P.cnt   = (unsigned*)w;                     // [0]=prep count, [32]=prep flag (1 KB)
    P.flg   = (unsigned*)(w + 1024);            // 256 flags, 128 B apart (32 KB)
    P.WtAll = (ushort*)(w + 1024 + 32768);      // 13 * 16384 bf16 (416 KB)
    P.pE    = (float*)(P.WtAll + 13 * 16384);   // 5 partial arrays, 256*128 f each
    P.pA0   = P.pE  + 256 * 128;
    P.pU0   = P.pA0 + 256 * 128;
    P.pA1   = P.pU0 + 256 * 128;
    P.pU1   = P.pA1 + 256 * 128;

    hipMemsetAsync(w, 0, 1024 + 32768, stream);   // counters + flags only
    k_gnn<<<dim3(256), dim3(256), 0, stream>>>(P);
}

// Round 8
// 140.257 us; speedup vs baseline: 2.4345x; 1.0669x over previous
//
#include <hip/hip_runtime.h>
#include <math.h>

// B=128, NU=32, NT=64, H=128, OUT_F=16, N_U=4096, N_A=8192
// Per-batch-local GNN (graph fully bipartite within batch). R8 structure:
// 256 blocks x 512 THREADS (8 waves): block (b,half) owns 16 hu + 32 ha rows.
// 8-way n-split halves per-wave stage work vs R7; 2 waves/SIMD hide latency
// (R7 ran 1 wave/SIMD: occupancy 10.7%, 50 us of exposed latency).
// it1 cu-side aggr dropped (dead). psyncs placed after independent stages.
// Weights pre-transposed [n][k] once (104 prep units + flag barrier).
// Coherence: cross-block data sc1 write-through, write-once, first-touch
// after flag sync; relaxed single-writer flags (no RMW storms, no inv/wbl2).

using frag  = __attribute__((ext_vector_type(8))) short;   // 8 x bf16
using f32x4 = __attribute__((ext_vector_type(4))) float;

#define LDST 136
#define SCOPE_AGT __HIP_MEMORY_SCOPE_AGENT

__device__ __forceinline__ float  bf2f(ushort u) { return __uint_as_float(((unsigned)u) << 16); }
__device__ __forceinline__ ushort f2bf(float f) {
    unsigned u = __float_as_uint(f);
    u += 0x7fff + ((u >> 16) & 1);            // RNE
    return (ushort)(u >> 16);
}
__device__ __forceinline__ void gst4_sc(void* p, unsigned v) {   // write-through to MALL
    asm volatile("global_store_dword %0, %1, off sc1" :: "v"(p), "v"(v) : "memory");
}

struct GP {
    const float *uf, *noise, *b_ue, *W_t, *b_t;
    const float *wsrc[13];    // fp32 weights for prep; slot 12 = W_ue
    const float *bias6[6];    // ca_aggr_b, ca_self_b, ca_comb_b, cu_aggr_b, cu_self_b, cu_comb_b
    const float *Wn, *bn;
    float *out;
    ushort *WtAll;            // 13 x [128][128] bf16 (n-major)
    float *pE, *pA0, *pU0, *pA1;   // per-block 128-f colsum partials
    unsigned *cnt, *flg;
};
// WtAll slots: 0,1 ca_aggr; 2,3 ca_self; 4,5 ca_comb; 6,7 cu_aggr;
//              8,9 cu_self; 10,11 cu_comb; 12 W_ue

__device__ __forceinline__ void psync(unsigned* myf, unsigned* pf, unsigned s) {
    asm volatile("s_waitcnt vmcnt(0)" ::: "memory");   // drain my sc1 stores
    __syncthreads();
    if (threadIdx.x == 0) {
        __hip_atomic_store(myf, s, __ATOMIC_RELAXED, SCOPE_AGT);
        while (__hip_atomic_load(pf, __ATOMIC_RELAXED, SCOPE_AGT) < s)
            __builtin_amdgcn_s_sleep(1);
    }
    __syncthreads();
}

// ---- MLP stage, 8 waves: wave w owns n-cols [16w,16w+16). MT m-tiles. ----
template<int MT, bool MEANADD>
__device__ __forceinline__ void mlp_stage(const ushort* Xl, ushort* Yl,
    const ushort* __restrict__ Wt, const float* __restrict__ bias, const float* meanL)
{
    const int lane = threadIdx.x & 63, wave = threadIdx.x >> 6;
    const int q = lane >> 4, l15 = lane & 15;
    const int n0 = wave * 16;
    frag A[4];
#pragma unroll
    for (int kc = 0; kc < 4; ++kc)
        A[kc] = *(const frag*)(Wt + (n0 + l15) * 128 + kc * 32 + q * 8);
    const float4 bv = *(const float4*)(bias + n0 + q * 4);
    float4 mv = {0.f, 0.f, 0.f, 0.f};
    if (MEANADD) mv = *(const float4*)(meanL + n0 + q * 4);
#pragma unroll
    for (int mt = 0; mt < MT; ++mt) {
        frag Bv[4];
#pragma unroll
        for (int kc = 0; kc < 4; ++kc)
            Bv[kc] = *(const frag*)(Xl + (mt * 16 + l15) * LDST + kc * 32 + q * 8);
        f32x4 acc = {0.f, 0.f, 0.f, 0.f};
#pragma unroll
        for (int kc = 0; kc < 4; ++kc)
            acc = __builtin_amdgcn_mfma_f32_16x16x32_bf16(A[kc], Bv[kc], acc, 0, 0, 0);
        float v0 = acc[0] + bv.x, v1 = acc[1] + bv.y, v2 = acc[2] + bv.z, v3 = acc[3] + bv.w;
        v0 = v0 > 0.f ? v0 : 0.f; v1 = v1 > 0.f ? v1 : 0.f;
        v2 = v2 > 0.f ? v2 : 0.f; v3 = v3 > 0.f ? v3 : 0.f;
        if (MEANADD) { v0 += mv.x; v1 += mv.y; v2 += mv.z; v3 += mv.w; }
        ushort4 o = { f2bf(v0), f2bf(v1), f2bf(v2), f2bf(v3) };
        *(ushort4*)(Yl + (mt * 16 + l15) * LDST + n0 + q * 4) = o;
    }
}

// ---- colsum over ROWS rows: own total -> ownDst (LDS) + sc1 global ----
template<int ROWS>
__device__ __forceinline__ void colsum(const ushort* buf, float* redL,
                                       float* ownDst, float* __restrict__ gDst)
{
    const int t = threadIdx.x, g = t >> 7, col = t & 127;
    float s = 0.f;
    for (int r = g; r < ROWS; r += 4) s += bf2f(buf[r * LDST + col]);
    redL[g * 128 + col] = s;
    __syncthreads();
    if (t < 128) {
        float tot = redL[t] + redL[128 + t] + redL[256 + t] + redL[384 + t];
        ownDst[t] = tot;
        gst4_sc(gDst + t, __float_as_uint(tot));
    }
    __syncthreads();
}

// ---- weight transpose slab (512-thread version) ----
__device__ __forceinline__ void wslab(ushort* dst, float* slab,
                                      const float* __restrict__ W, int kb)
{
    {
        const int c = threadIdx.x;              // 512 items exactly
        const int kr = c >> 5, c4 = c & 31;
        const float4 v = *(const float4*)(W + (kb * 16 + kr) * 128 + c4 * 4);
        slab[kr * 129 + c4 * 4 + 0] = v.x; slab[kr * 129 + c4 * 4 + 1] = v.y;
        slab[kr * 129 + c4 * 4 + 2] = v.z; slab[kr * 129 + c4 * 4 + 3] = v.w;
    }
    __syncthreads();
    for (int c = threadIdx.x; c < 1024; c += 512) {
        const int n = c >> 3, k2 = c & 7;
        const unsigned d = (unsigned)f2bf(slab[(2 * k2) * 129 + n])
                         | ((unsigned)f2bf(slab[(2 * k2 + 1) * 129 + n]) << 16);
        gst4_sc(dst + n * 128 + kb * 16 + 2 * k2, d);
    }
    __syncthreads();
}

__global__ __launch_bounds__(512, 1) void k_gnn(GP P)
{
    __shared__ __align__(16) ushort HU [16 * LDST];
    __shared__ __align__(16) ushort HU2[16 * LDST];
    __shared__ __align__(16) ushort HA [32 * LDST];
    __shared__ __align__(16) ushort HA2[32 * LDST];
    __shared__ __align__(16) ushort T0 [32 * LDST];
    __shared__ __align__(16) ushort T1 [32 * LDST];
    __shared__ float meanP[128], meanQ[128], antL[128], redL[512];

    const int blk = blockIdx.x, tid = threadIdx.x;
    const int b = blk >> 1, half = blk & 1;
    unsigned* myf = P.flg + blk * 32;
    unsigned* prf = P.flg + (blk ^ 1) * 32;
    const int prt = blk ^ 1;
    const ushort* Wt = P.WtAll;
    const float* const* bb = P.bias6;

    // ---- weight prep (104 of 256 blocks; slab temp in T1) ----
    if (blk < 104)
        wslab(P.WtAll + (blk >> 3) * 16384, (float*)T1, P.wsrc[blk >> 3], blk & 7);

    // stage own 16 uf rows -> T0 (input: no coherence concern)
    {
        const int c = tid;                      // 512 items exactly
        const int r = c >> 5, k4 = c & 31;
        const float4 v = *(const float4*)(P.uf + (size_t)(b * 32 + half * 16 + r) * 128 + k4 * 4);
        ushort4 o = { f2bf(v.x), f2bf(v.y), f2bf(v.z), f2bf(v.w) };
        *(ushort4*)(T0 + r * LDST + k4 * 4) = o;
    }
    // stage own 32 noise rows -> HA (ant added in-place later)
    for (int c = tid; c < 1024; c += 512) {
        const int r = c >> 5, k4 = c & 31;
        const float4 v = *(const float4*)(P.noise + (size_t)(b * 64 + half * 32 + r) * 128 + k4 * 4);
        ushort4 o = { f2bf(v.x), f2bf(v.y), f2bf(v.z), f2bf(v.w) };
        *(ushort4*)(HA + r * LDST + k4 * 4) = o;
    }

    // ---- global prep barrier: last arriver broadcasts flag ----
    asm volatile("s_waitcnt vmcnt(0)" ::: "memory");
    __syncthreads();
    if (tid == 0) {
        if (blk < 104) {
            unsigned old = __hip_atomic_fetch_add(P.cnt, 1u, __ATOMIC_RELAXED, SCOPE_AGT);
            if (old == 103u) __hip_atomic_store(P.cnt + 32, 1u, __ATOMIC_RELAXED, SCOPE_AGT);
        }
        while (__hip_atomic_load(P.cnt + 32, __ATOMIC_RELAXED, SCOPE_AGT) < 1u)
            __builtin_amdgcn_s_sleep(4);
    }
    __syncthreads();

    // ---- embed + colsumE; then aggr-hu msgs + colsumA0; one psync for both ----
    mlp_stage<1, false>(T0, HU, Wt + 12 * 16384, P.b_ue, nullptr);
    __syncthreads();
    colsum<16>(HU, redL, meanP, P.pE + blk * 128);          // meanP = own E total
    mlp_stage<1, false>(HU, T0, Wt + 0 * 16384, bb[0], nullptr);
    __syncthreads();
    mlp_stage<1, false>(T0, T1, Wt + 1 * 16384, bb[0] + 128, nullptr);
    __syncthreads();
    colsum<16>(T1, redL, meanQ, P.pA0 + blk * 128);         // meanQ = own A0 total
    psync(myf, prf, 1u);

    // ---- ant = relu((E_own+E_prt)/32 @ W_t + b_t); HA += ant ----
    if (tid < 128) meanP[tid] = (meanP[tid] + P.pE[prt * 128 + tid]) * (1.f / 32.f);
    __syncthreads();
    {
        const int g = tid >> 7, col = tid & 127;
        float s = 0.f;
#pragma unroll 4
        for (int k = g * 32; k < g * 32 + 32; ++k) s += meanP[k] * P.W_t[k * 128 + col];
        redL[g * 128 + col] = s;
    }
    __syncthreads();
    if (tid < 128) {
        float a = P.b_t[tid] + redL[tid] + redL[128 + tid] + redL[256 + tid] + redL[384 + tid];
        antL[tid] = a > 0.f ? a : 0.f;
    }
    __syncthreads();
    for (int c = tid; c < 1024; c += 512) {
        const int r = c >> 5, k4 = c & 31;
        ushort4 h = *(ushort4*)(HA + r * LDST + k4 * 4);
        ushort4 o = { f2bf(bf2f(h.x) + antL[k4 * 4 + 0]), f2bf(bf2f(h.y) + antL[k4 * 4 + 1]),
                      f2bf(bf2f(h.z) + antL[k4 * 4 + 2]), f2bf(bf2f(h.w) + antL[k4 * 4 + 3]) };
        *(ushort4*)(HA + r * LDST + k4 * 4) = o;
    }
    __syncthreads();

    // ---- it0 aggr-ha msgs + colsumU0; overlap psync2 with comb-ha stage 1 ----
    mlp_stage<2, false>(HA, T0, Wt + 6 * 16384, bb[3], nullptr);
    __syncthreads();
    mlp_stage<2, false>(T0, T1, Wt + 7 * 16384, bb[3] + 128, nullptr);
    __syncthreads();
    colsum<32>(T1, redL, meanP, P.pU0 + blk * 128);         // meanP = own U0 total
    mlp_stage<2, false>(HA, T0, Wt + 2 * 16384, bb[1], nullptr);   // ca_self L0
    __syncthreads();
    psync(myf, prf, 2u);

    // ---- it0 comb-ha (uses meanA0), comb-hu (uses meanU0) ----
    if (tid < 128) {
        meanQ[tid] = (meanQ[tid] + P.pA0[prt * 128 + tid]) * (1.f / 32.f);
        meanP[tid] = (meanP[tid] + P.pU0[prt * 128 + tid]) * (1.f / 64.f);
    }
    __syncthreads();
    mlp_stage<2, true >(T0, T1, Wt + 3 * 16384, bb[1] + 128, meanQ);
    __syncthreads();
    mlp_stage<2, false>(T1, T0, Wt + 4 * 16384, bb[2], nullptr);
    __syncthreads();
    mlp_stage<2, false>(T0, HA2, Wt + 5 * 16384, bb[2] + 128, nullptr);
    __syncthreads();
    mlp_stage<1, false>(HU, T0, Wt + 8 * 16384, bb[4], nullptr);   // cu_self L0
    __syncthreads();
    mlp_stage<1, true >(T0, T1, Wt + 9 * 16384, bb[4] + 128, meanP);
    __syncthreads();
    mlp_stage<1, false>(T1, T0, Wt + 10 * 16384, bb[5], nullptr);
    __syncthreads();
    mlp_stage<1, false>(T0, HU2, Wt + 11 * 16384, bb[5] + 128, nullptr);
    __syncthreads();

    // ---- it1: aggr on hu2 only (cu-side of it1 is dead) ----
    mlp_stage<1, false>(HU2, T0, Wt + 0 * 16384, bb[0], nullptr);
    __syncthreads();
    mlp_stage<1, false>(T0, T1, Wt + 1 * 16384, bb[0] + 128, nullptr);
    __syncthreads();
    colsum<16>(T1, redL, meanQ, P.pA1 + blk * 128);         // meanQ = own A1 total
    mlp_stage<2, false>(HA2, T0, Wt + 2 * 16384, bb[1], nullptr);  // ca_self L0 (overlap)
    __syncthreads();
    psync(myf, prf, 3u);

    // ---- it1 comb-ha + fused final normalize ----
    if (tid < 128) meanQ[tid] = (meanQ[tid] + P.pA1[prt * 128 + tid]) * (1.f / 32.f);
    __syncthreads();
    mlp_stage<2, true >(T0, T1, Wt + 3 * 16384, bb[1] + 128, meanQ);
    __syncthreads();
    mlp_stage<2, false>(T1, T0, Wt + 4 * 16384, bb[2], nullptr);
    __syncthreads();
    mlp_stage<2, false>(T0, T1, Wt + 5 * 16384, bb[2] + 128, nullptr);
    __syncthreads();

    float* WnS = (float*)T0;                    // 8 KB <= T0 (8.7 KB)
    {
        const int c = tid;                      // 512 float4 = 2048 floats
        *(float4*)(WnS + c * 4) = *(const float4*)(P.Wn + c * 4);
    }
    __syncthreads();
    {
        const int row = tid >> 4, j = tid & 15; // 32 rows x 16 cols = 512
        float acc = P.bn[j];
        const ushort* h = T1 + row * LDST;
#pragma unroll 4
        for (int k = 0; k < 128; ++k) acc += bf2f(h[k]) * WnS[k * 16 + j];
        redL[row * 16 + j] = acc;
        __syncthreads();
        const float re = redL[row * 16 + (j & 7)], im = redL[row * 16 + (j & 7) + 8];
        const float mag = sqrtf(re * re + im * im);
        const int a = b * 64 + half * 32 + row;
        P.out[a * 16 + j] = acc / mag;
    }
}

extern "C" void kernel_launch(void* const* d_in, const int* in_sizes, int n_in,
                              void* d_out, int out_size, void* d_ws, size_t ws_size,
                              hipStream_t stream)
{
    GP P;
    P.uf    = (const float*)d_in[0];
    P.noise = (const float*)d_in[1];
    const float* W_ue = (const float*)d_in[6];
    P.b_ue  = (const float*)d_in[7];
    P.W_t   = (const float*)d_in[8];
    P.b_t   = (const float*)d_in[9];
    const float* caW[3] = {(const float*)d_in[10], (const float*)d_in[12], (const float*)d_in[14]};
    const float* cab[3] = {(const float*)d_in[11], (const float*)d_in[13], (const float*)d_in[15]};
    const float* cuW[3] = {(const float*)d_in[16], (const float*)d_in[18], (const float*)d_in[20]};
    const float* cub[3] = {(const float*)d_in[17], (const float*)d_in[19], (const float*)d_in[21]};
    P.Wn  = (const float*)d_in[22];
    P.bn  = (const float*)d_in[23];
    P.out = (float*)d_out;

    P.wsrc[0]  = caW[0]; P.wsrc[1]  = caW[0] + 16384;
    P.wsrc[2]  = caW[1]; P.wsrc[3]  = caW[1] + 16384;
    P.wsrc[4]  = caW[2]; P.wsrc[5]  = caW[2] + 16384;
    P.wsrc[6]  = cuW[0]; P.wsrc[7]  = cuW[0] + 16384;
    P.wsrc[8]  = cuW[1]; P.wsrc[9]  = cuW[1] + 16384;
    P.wsrc[10] = cuW[2]; P.wsrc[11] = cuW[2] + 16384;
    P.wsrc[12] = W_ue;
    P.bias6[0] = cab[0]; P.bias6[1] = cab[1]; P.bias6[2] = cab[2];
    P.bias6[3] = cub[0]; P.bias6[4] = cub[1]; P.bias6[5] = cub[2];

    char* w = (char*)d_ws;
    P.cnt   = (unsigned*)w;                     // [0]=prep count, [32]=prep flag (1 KB)
    P.flg   = (unsigned*)(w + 1024);            // 256 flags, 128 B apart (32 KB)
    P.WtAll = (ushort*)(w + 1024 + 32768);      // 13 * 16384 bf16 (416 KB)
    P.pE    = (float*)(P.WtAll + 13 * 16384);   // 4 partial arrays, 256*128 f each
    P.pA0   = P.pE  + 256 * 128;
    P.pU0   = P.pA0 + 256 * 128;
    P.pA1   = P.pU0 + 256 * 128;

    hipMemsetAsync(w, 0, 1024 + 32768, stream);   // counters + flags only
    k_gnn<<<dim3(256), dim3(512), 0, stream>>>(P);
}